// Round 2
// baseline (1143.352 us; speedup 1.0000x reference)
//
#include <hip/hip_runtime.h>
#include <hip/hip_bf16.h>
#include <stdint.h>

#define C_    512
#define T_    24
#define HWSZ  1024
#define NN    4096
#define JTOT  98304   // T_*NN
#define EPSV  1e-5f

typedef short short8 __attribute__((ext_vector_type(8)));
typedef float f32x4 __attribute__((ext_vector_type(4)));

typedef __attribute__((address_space(1))) const uint32_t glob_u32;
typedef __attribute__((address_space(3))) uint32_t lds_u32;

__device__ __forceinline__ unsigned short f2bf(float f) {
  union { float f; unsigned u; } v; v.f = f;
  unsigned r = v.u + 0x7fffu + ((v.u >> 16) & 1u);
  return (unsigned short)(r >> 16);
}
__device__ __forceinline__ float bf2f(unsigned short b) {
  union { unsigned u; float f; } v; v.u = ((unsigned)b) << 16;
  return v.f;
}

__device__ __forceinline__ void gload_lds16(const void* g, void* l) {
  __builtin_amdgcn_global_load_lds((glob_u32*)g, (lds_u32*)l, 16, 0, 0);
}

// ---------------- K0: weight f32 -> bf16 ----------------
__global__ void k_cvt(const float* __restrict__ qkvw, const float* __restrict__ projw,
                      unsigned short* __restrict__ qkvw_bf, unsigned short* __restrict__ projw_bf) {
  int i = blockIdx.x * 256 + threadIdx.x;
  if (i < 786432) qkvw_bf[i] = f2bf(qkvw[i]);
  if (i < 262144) projw_bf[i] = f2bf(projw[i]);
}

// ---------------- K1a: GroupNorm stats ----------------
// grid: 2048 = (g 32) x (hwt 16) x (b 4), block 256
__global__ __launch_bounds__(256) void k_stats(const float* __restrict__ x,
                                               float* __restrict__ mean, float* __restrict__ rstd) {
  int bid = blockIdx.x;
  int g = bid & 31, hwt = (bid >> 5) & 15, b = bid >> 9;
  int tid = threadIdx.x, lane = tid & 63, grp = tid >> 6;
  int hw = hwt * 64 + lane;
  float s = 0.f, sq = 0.f;
  for (int ct = grp; ct < 384; ct += 4) {
    int c = g * 16 + ct / 24;
    int t = ct % 24;
    float v = x[((size_t)((b * 512 + c) * 24 + t) << 10) + hw];
    s += v; sq += v * v;
  }
  __shared__ float ls[4][64], lq[4][64];
  ls[grp][lane] = s; lq[grp][lane] = sq;
  __syncthreads();
  if (tid < 64) {
    float S = ls[0][tid] + ls[1][tid] + ls[2][tid] + ls[3][tid];
    float Q = lq[0][tid] + lq[1][tid] + lq[2][tid] + lq[3][tid];
    float m = S * (1.f / 384.f);
    float var = Q * (1.f / 384.f) - m * m;
    int n = b * HWSZ + hwt * 64 + tid;
    mean[n * 32 + g] = m;
    rstd[n * 32 + g] = rsqrtf(var + EPSV);
  }
}

// ---------------- K1b: normalize + transpose to Xn[j][c] bf16 ----------------
// grid: 1536 = (hwt 16) x (t 24) x (b 4), block 256
__global__ __launch_bounds__(256) void k_norm(const float* __restrict__ x,
                                              const float* __restrict__ mean, const float* __restrict__ rstd,
                                              const float* __restrict__ gnw, const float* __restrict__ gnb,
                                              unsigned short* __restrict__ xn) {
  __shared__ unsigned short xs[C_][66];
  int bid = blockIdx.x;
  int hwt = bid & 15, tb = bid >> 4;
  int t = tb % 24, b = tb / 24;
  int tid = threadIdx.x, lane = tid & 63, grp = tid >> 6;
  int hw = hwt * 64 + lane;
  int n = b * HWSZ + hw;
  for (int c = grp; c < C_; c += 4) {
    float v = x[((size_t)((b * 512 + c) * 24 + t) << 10) + hw];
    int g = c >> 4;
    float xv = (v - mean[n * 32 + g]) * rstd[n * 32 + g] * gnw[c] + gnb[c];
    xs[c][lane] = f2bf(xv);
  }
  __syncthreads();
  int w = grp, l = lane;
  for (int p = 0; p < 16; ++p) {
    int nl = p * 4 + w;
    size_t j = (size_t)t * NN + b * HWSZ + hwt * 64 + nl;
    unsigned short tmp[8] __attribute__((aligned(16)));
#pragma unroll
    for (int m = 0; m < 8; ++m) tmp[m] = xs[l * 8 + m][nl];
    *reinterpret_cast<uint4*>(&xn[j * C_ + l * 8]) = *reinterpret_cast<const uint4*>(tmp);
  }
}

// ---------------- K2/K4: bf16 MFMA GEMM (gemm_bt; m97 structure) ----------------
// C[m][j] = sum_k A[m][k] * B[j][k];  grid (JTOT/128, M/128), block 256
template <int MODE>
__global__ __launch_bounds__(256, 2) void k_gemm(
    const unsigned short* __restrict__ A,   // [M][512] bf16
    const unsigned short* __restrict__ B,   // [JTOT][512] bf16
    const float* __restrict__ bias,         // [M]
    unsigned short* __restrict__ outb,      // MODE0: [M][JTOT] bf16
    const float* __restrict__ xres,         // MODE1: residual source
    float* __restrict__ outf) {             // MODE1: final f32 out
  __shared__ __attribute__((aligned(16))) unsigned short As[128 * 64];
  __shared__ __attribute__((aligned(16))) unsigned short Bs[128 * 64];
  const int jt = blockIdx.x, mt = blockIdx.y;
  const int j0 = jt * 128, m0 = mt * 128;
  const int tid = threadIdx.x;
  const int wave = tid >> 6, lane = tid & 63;
  const int l16 = lane & 15, lqq = lane >> 4;
  const int wm = wave >> 1, wn = wave & 1;
  const int srow = lane >> 3, sseg = lane & 7;

  f32x4 acc[4][4];
#pragma unroll
  for (int i = 0; i < 4; ++i)
#pragma unroll
    for (int j = 0; j < 4; ++j) acc[i][j] = {0.f, 0.f, 0.f, 0.f};

  for (int kt = 0; kt < 512; kt += 64) {
#pragma unroll
    for (int i = 0; i < 4; ++i) {
      const int chunk = i * 4 + wave;
      const int r = chunk * 8 + srow;
      gload_lds16(A + ((size_t)(m0 + r) * 512 + kt + sseg * 8), &As[chunk * 512]);
    }
#pragma unroll
    for (int i = 0; i < 4; ++i) {
      const int chunk = i * 4 + wave;
      const int r = chunk * 8 + srow;
      gload_lds16(B + ((size_t)(j0 + r) * 512 + kt + sseg * 8), &Bs[chunk * 512]);
    }
    __syncthreads();
#pragma unroll
    for (int ks = 0; ks < 2; ++ks) {
      short8 af[4], bfr[4];
#pragma unroll
      for (int i = 0; i < 4; ++i)
        af[i] = *reinterpret_cast<const short8*>(&As[(wm * 64 + i * 16 + l16) * 64 + ks * 32 + lqq * 8]);
#pragma unroll
      for (int i = 0; i < 4; ++i)
        bfr[i] = *reinterpret_cast<const short8*>(&Bs[(wn * 64 + i * 16 + l16) * 64 + ks * 32 + lqq * 8]);
#pragma unroll
      for (int mi = 0; mi < 4; ++mi)
#pragma unroll
        for (int ni = 0; ni < 4; ++ni)
          acc[mi][ni] = __builtin_amdgcn_mfma_f32_16x16x32_bf16(af[mi], bfr[ni], acc[mi][ni], 0, 0, 0);
    }
    __syncthreads();
  }

#pragma unroll
  for (int mi = 0; mi < 4; ++mi) {
#pragma unroll
    for (int ni = 0; ni < 4; ++ni) {
      const int dbase = m0 + wm * 64 + mi * 16 + lqq * 4;
      const int jj = j0 + wn * 64 + ni * 16 + l16;
      if (MODE == 0) {
#pragma unroll
        for (int r = 0; r < 4; ++r) {
          float v = acc[mi][ni][r] + bias[dbase + r];
          outb[(size_t)(dbase + r) * JTOT + jj] = f2bf(v);
        }
      } else {
        const int t = jj >> 12, n = jj & 4095;
        const int b = n >> 10, hw = n & 1023;
#pragma unroll
        for (int r = 0; r < 4; ++r) {
          size_t o = (((size_t)(b * 512 + dbase + r) * 24 + t) << 10) + hw;
          outf[o] = xres[o] + acc[mi][ni][r] + bias[dbase + r];
        }
      }
    }
  }
}

// ---------------- K3: attention (VALU f32, lane = n) ----------------
// grid (64 ntile, 8 h), block 512: lane=n (64), slot=t-group (8, 3 t each)
__global__ __launch_bounds__(512) void k_attn(const unsigned short* __restrict__ qkv,
                                              unsigned short* __restrict__ ao) {
  __shared__ unsigned short ks_[8][24][64];
  __shared__ unsigned short qs_[8][24][64];
  const int ntile = blockIdx.x, h = blockIdx.y;
  const int n0 = ntile * 64;
  const int tid = threadIdx.x;
  const int lane = tid & 63, slot = tid >> 6;
  const size_t baseq = (size_t)(h * 64) * JTOT;
  const size_t basek = (size_t)(512 + h * 64) * JTOT;
  const size_t basev = (size_t)(1024 + h * 64) * JTOT;

  float S[3][24];
#pragma unroll
  for (int a = 0; a < 3; ++a)
#pragma unroll
    for (int s = 0; s < 24; ++s) S[a][s] = 0.f;

  for (int dc = 0; dc < 64; dc += 8) {
    for (int i = 0; i < 48; ++i) {
      int rowid = (i << 3) + slot;
      int isK = rowid >= 192;
      int rr = isK ? rowid - 192 : rowid;
      int d = rr / 24, t = rr - d * 24;
      unsigned short v = qkv[(isK ? basek : baseq) + (size_t)(dc + d) * JTOT + t * NN + n0 + lane];
      if (isK) ks_[d][t][lane] = v; else qs_[d][t][lane] = v;
    }
    __syncthreads();
    float qf[3][8];
#pragma unroll
    for (int a = 0; a < 3; ++a)
#pragma unroll
      for (int d = 0; d < 8; ++d)
        qf[a][d] = bf2f(qs_[d][slot * 3 + a][lane]);
    for (int d = 0; d < 8; ++d) {
#pragma unroll
      for (int s = 0; s < 24; ++s) {
        float kv = bf2f(ks_[d][s][lane]);
        S[0][s] = fmaf(qf[0][d], kv, S[0][s]);
        S[1][s] = fmaf(qf[1][d], kv, S[1][s]);
        S[2][s] = fmaf(qf[2][d], kv, S[2][s]);
      }
    }
    __syncthreads();
  }

#pragma unroll
  for (int a = 0; a < 3; ++a) {
    float mx = S[a][0];
#pragma unroll
    for (int s = 1; s < 24; ++s) mx = fmaxf(mx, S[a][s]);
    float sum = 0.f;
#pragma unroll
    for (int s = 0; s < 24; ++s) {
      float e = __expf((S[a][s] - mx) * 0.125f);
      S[a][s] = e; sum += e;
    }
    float inv = 1.f / sum;
#pragma unroll
    for (int s = 0; s < 24; ++s) S[a][s] *= inv;
  }

  for (int dc = 0; dc < 64; dc += 8) {
    for (int i = 0; i < 24; ++i) {
      int rowid = (i << 3) + slot;
      int d = rowid / 24, s = rowid - d * 24;
      qs_[d][s][lane] = qkv[basev + (size_t)(dc + d) * JTOT + s * NN + n0 + lane];
    }
    __syncthreads();
    float o[3][8];
#pragma unroll
    for (int a = 0; a < 3; ++a)
#pragma unroll
      for (int d = 0; d < 8; ++d) o[a][d] = 0.f;
#pragma unroll
    for (int d = 0; d < 8; ++d) {
#pragma unroll
      for (int s = 0; s < 24; ++s) {
        float vv = bf2f(qs_[d][s][lane]);
        o[0][d] = fmaf(S[0][s], vv, o[0][d]);
        o[1][d] = fmaf(S[1][s], vv, o[1][d]);
        o[2][d] = fmaf(S[2][s], vv, o[2][d]);
      }
    }
#pragma unroll
    for (int a = 0; a < 3; ++a) {
      int t = slot * 3 + a;
      size_t j = (size_t)t * NN + n0 + lane;
      unsigned short tmp[8] __attribute__((aligned(16)));
#pragma unroll
      for (int d = 0; d < 8; ++d) tmp[d] = f2bf(o[a][d]);
      *reinterpret_cast<uint4*>(&ao[j * C_ + h * 64 + dc]) = *reinterpret_cast<const uint4*>(tmp);
    }
    __syncthreads();
  }
}

extern "C" void kernel_launch(void* const* d_in, const int* in_sizes, int n_in,
                              void* d_out, int out_size, void* d_ws, size_t ws_size,
                              hipStream_t stream) {
  (void)in_sizes; (void)n_in; (void)out_size; (void)ws_size;
  const float* x     = (const float*)d_in[0];
  const float* gnw   = (const float*)d_in[1];
  const float* gnb   = (const float*)d_in[2];
  const float* qkvw  = (const float*)d_in[3];
  const float* qkvb  = (const float*)d_in[4];
  const float* projw = (const float*)d_in[5];
  const float* projb = (const float*)d_in[6];
  float* out = (float*)d_out;
  char* ws = (char*)d_ws;

  unsigned short* qkvw_bf = (unsigned short*)(ws);                    // 1,572,864 B
  unsigned short* projw_bf = (unsigned short*)(ws + 1572864);         //   524,288 B
  float* mean = (float*)(ws + 2097152);                               //   524,288 B
  float* rstd = (float*)(ws + 2621440);                               //   524,288 B
  unsigned short* xn  = (unsigned short*)(ws + 3145728);              // 100,663,296 B (also attnout)
  unsigned short* qkv = (unsigned short*)(ws + 3145728 + 100663296);  // 301,989,888 B

  k_cvt<<<dim3(3072), dim3(256), 0, stream>>>(qkvw, projw, qkvw_bf, projw_bf);
  k_stats<<<dim3(2048), dim3(256), 0, stream>>>(x, mean, rstd);
  k_norm<<<dim3(1536), dim3(256), 0, stream>>>(x, mean, rstd, gnw, gnb, xn);
  k_gemm<0><<<dim3(768, 12), dim3(256), 0, stream>>>(qkvw_bf, xn, qkvb, qkv, nullptr, nullptr);
  k_attn<<<dim3(64, 8), dim3(512), 0, stream>>>(qkv, xn);  // attnout overwrites xn
  k_gemm<1><<<dim3(768, 4), dim3(256), 0, stream>>>(projw_bf, xn, projb, nullptr, x, out);
}

// Round 3
// 819.358 us; speedup vs baseline: 1.3954x; 1.3954x over previous
//
#include <hip/hip_runtime.h>
#include <hip/hip_bf16.h>
#include <stdint.h>

#define C_    512
#define T_    24
#define HWSZ  1024
#define NN    4096
#define JTOT  98304   // T_*NN
#define EPSV  1e-5f

typedef short short8 __attribute__((ext_vector_type(8)));
typedef float f32x4 __attribute__((ext_vector_type(4)));

typedef __attribute__((address_space(1))) const uint32_t glob_u32;
typedef __attribute__((address_space(3))) uint32_t lds_u32;

__device__ __forceinline__ unsigned short f2bf(float f) {
  union { float f; unsigned u; } v; v.f = f;
  unsigned r = v.u + 0x7fffu + ((v.u >> 16) & 1u);
  return (unsigned short)(r >> 16);
}
__device__ __forceinline__ float bf2f(unsigned short b) {
  union { unsigned u; float f; } v; v.u = ((unsigned)b) << 16;
  return v.f;
}
__device__ __forceinline__ float bflo(uint32_t u) {
  union { unsigned u; float f; } v; v.u = u << 16; return v.f;
}
__device__ __forceinline__ float bfhi(uint32_t u) {
  union { unsigned u; float f; } v; v.u = u & 0xffff0000u; return v.f;
}
__device__ __forceinline__ uint32_t pkbf(float a, float b) {
  return (uint32_t)f2bf(a) | ((uint32_t)f2bf(b) << 16);
}

__device__ __forceinline__ void gload_lds16(const void* g, void* l) {
  __builtin_amdgcn_global_load_lds((glob_u32*)g, (lds_u32*)l, 16, 0, 0);
}

// ---------------- K0: weight f32 -> bf16 ----------------
__global__ void k_cvt(const float* __restrict__ qkvw, const float* __restrict__ projw,
                      unsigned short* __restrict__ qkvw_bf, unsigned short* __restrict__ projw_bf) {
  int i = blockIdx.x * 256 + threadIdx.x;
  if (i < 786432) qkvw_bf[i] = f2bf(qkvw[i]);
  if (i < 262144) projw_bf[i] = f2bf(projw[i]);
}

// ---------------- K1a: GroupNorm stats ----------------
__global__ __launch_bounds__(256) void k_stats(const float* __restrict__ x,
                                               float* __restrict__ mean, float* __restrict__ rstd) {
  int bid = blockIdx.x;
  int g = bid & 31, hwt = (bid >> 5) & 15, b = bid >> 9;
  int tid = threadIdx.x, lane = tid & 63, grp = tid >> 6;
  int hw = hwt * 64 + lane;
  float s = 0.f, sq = 0.f;
  for (int ct = grp; ct < 384; ct += 4) {
    int c = g * 16 + ct / 24;
    int t = ct % 24;
    float v = x[((size_t)((b * 512 + c) * 24 + t) << 10) + hw];
    s += v; sq += v * v;
  }
  __shared__ float ls[4][64], lq[4][64];
  ls[grp][lane] = s; lq[grp][lane] = sq;
  __syncthreads();
  if (tid < 64) {
    float S = ls[0][tid] + ls[1][tid] + ls[2][tid] + ls[3][tid];
    float Q = lq[0][tid] + lq[1][tid] + lq[2][tid] + lq[3][tid];
    float m = S * (1.f / 384.f);
    float var = Q * (1.f / 384.f) - m * m;
    int n = b * HWSZ + hwt * 64 + tid;
    mean[n * 32 + g] = m;
    rstd[n * 32 + g] = rsqrtf(var + EPSV);
  }
}

// ---------------- K1b: normalize + transpose to Xn[j][c] bf16 ----------------
__global__ __launch_bounds__(256) void k_norm(const float* __restrict__ x,
                                              const float* __restrict__ mean, const float* __restrict__ rstd,
                                              const float* __restrict__ gnw, const float* __restrict__ gnb,
                                              unsigned short* __restrict__ xn) {
  __shared__ unsigned short xs[C_][66];
  int bid = blockIdx.x;
  int hwt = bid & 15, tb = bid >> 4;
  int t = tb % 24, b = tb / 24;
  int tid = threadIdx.x, lane = tid & 63, grp = tid >> 6;
  int hw = hwt * 64 + lane;
  int n = b * HWSZ + hw;
  for (int c = grp; c < C_; c += 4) {
    float v = x[((size_t)((b * 512 + c) * 24 + t) << 10) + hw];
    int g = c >> 4;
    float xv = (v - mean[n * 32 + g]) * rstd[n * 32 + g] * gnw[c] + gnb[c];
    xs[c][lane] = f2bf(xv);
  }
  __syncthreads();
  int w = grp, l = lane;
  for (int p = 0; p < 16; ++p) {
    int nl = p * 4 + w;
    size_t j = (size_t)t * NN + b * HWSZ + hwt * 64 + nl;
    unsigned short tmp[8] __attribute__((aligned(16)));
#pragma unroll
    for (int m = 0; m < 8; ++m) tmp[m] = xs[l * 8 + m][nl];
    *reinterpret_cast<uint4*>(&xn[j * C_ + l * 8]) = *reinterpret_cast<const uint4*>(tmp);
  }
}

// ---------------- K2/K4: bf16 MFMA GEMM (gemm_bt; m97 structure) ----------------
// MODE0: B = [JTOT][512] row-major.  MODE1: B = chunked [64 kc][JTOT][8].
template <int MODE>
__global__ __launch_bounds__(256, 2) void k_gemm(
    const unsigned short* __restrict__ A,   // [M][512] bf16
    const unsigned short* __restrict__ B,
    const float* __restrict__ bias,         // [M]
    unsigned short* __restrict__ outb,      // MODE0: [M][JTOT] bf16
    const float* __restrict__ xres,         // MODE1: residual source
    float* __restrict__ outf) {             // MODE1: final f32 out
  __shared__ __attribute__((aligned(16))) unsigned short As[128 * 64];
  __shared__ __attribute__((aligned(16))) unsigned short Bs[128 * 64];
  const int jt = blockIdx.x, mt = blockIdx.y;
  const int j0 = jt * 128, m0 = mt * 128;
  const int tid = threadIdx.x;
  const int wave = tid >> 6, lane = tid & 63;
  const int l16 = lane & 15, lqq = lane >> 4;
  const int wm = wave >> 1, wn = wave & 1;
  const int srow = lane >> 3, sseg = lane & 7;

  f32x4 acc[4][4];
#pragma unroll
  for (int i = 0; i < 4; ++i)
#pragma unroll
    for (int j = 0; j < 4; ++j) acc[i][j] = {0.f, 0.f, 0.f, 0.f};

  for (int kt = 0; kt < 512; kt += 64) {
#pragma unroll
    for (int i = 0; i < 4; ++i) {
      const int chunk = i * 4 + wave;
      const int r = chunk * 8 + srow;
      gload_lds16(A + ((size_t)(m0 + r) * 512 + kt + sseg * 8), &As[chunk * 512]);
    }
    if (MODE == 0) {
#pragma unroll
      for (int i = 0; i < 4; ++i) {
        const int chunk = i * 4 + wave;
        const int r = chunk * 8 + srow;
        gload_lds16(B + ((size_t)(j0 + r) * 512 + kt + sseg * 8), &Bs[chunk * 512]);
      }
    } else {
      // chunked B: unit u = kc*128 + jr ; global (kt/8 + kc)*JTOT*8 + (j0+jr)*8
#pragma unroll
      for (int p = 0; p < 4; ++p) {
        const int u = p * 256 + tid;
        const int kc = u >> 7, jr = u & 127;
        gload_lds16(B + ((size_t)((kt >> 3) + kc) * JTOT + (j0 + jr)) * 8, &Bs[(size_t)u * 8]);
      }
    }
    __syncthreads();
#pragma unroll
    for (int ks = 0; ks < 2; ++ks) {
      short8 af[4], bfr[4];
#pragma unroll
      for (int i = 0; i < 4; ++i)
        af[i] = *reinterpret_cast<const short8*>(&As[(wm * 64 + i * 16 + l16) * 64 + ks * 32 + lqq * 8]);
#pragma unroll
      for (int i = 0; i < 4; ++i) {
        if (MODE == 0)
          bfr[i] = *reinterpret_cast<const short8*>(&Bs[(wn * 64 + i * 16 + l16) * 64 + ks * 32 + lqq * 8]);
        else
          bfr[i] = *reinterpret_cast<const short8*>(&Bs[(((ks * 4 + lqq) * 128) + wn * 64 + i * 16 + l16) * 8]);
      }
#pragma unroll
      for (int mi = 0; mi < 4; ++mi)
#pragma unroll
        for (int ni = 0; ni < 4; ++ni)
          acc[mi][ni] = __builtin_amdgcn_mfma_f32_16x16x32_bf16(af[mi], bfr[ni], acc[mi][ni], 0, 0, 0);
    }
    __syncthreads();
  }

#pragma unroll
  for (int mi = 0; mi < 4; ++mi) {
#pragma unroll
    for (int ni = 0; ni < 4; ++ni) {
      const int dbase = m0 + wm * 64 + mi * 16 + lqq * 4;
      const int jj = j0 + wn * 64 + ni * 16 + l16;
      if (MODE == 0) {
#pragma unroll
        for (int r = 0; r < 4; ++r) {
          float v = acc[mi][ni][r] + bias[dbase + r];
          outb[(size_t)(dbase + r) * JTOT + jj] = f2bf(v);
        }
      } else {
        const int t = jj >> 12, n = jj & 4095;
        const int b = n >> 10, hw = n & 1023;
#pragma unroll
        for (int r = 0; r < 4; ++r) {
          size_t o = (((size_t)(b * 512 + dbase + r) * 24 + t) << 10) + hw;
          outf[o] = xres[o] + acc[mi][ni][r] + bias[dbase + r];
        }
      }
    }
  }
}

// ---------------- K3: attention (VALU f32, lane = n, d-pair packed LDS) ----------------
// grid (64 ntile, 8 h), block 512: lane=n (64), slot owns 3 t's.
// Output layout: aoC[kc=(k>>3)][j][k&7], k = h*64 + d  -> per-chunk uint4 stores coalesced.
__global__ __launch_bounds__(512) void k_attn(const unsigned short* __restrict__ qkv,
                                              unsigned short* __restrict__ aoC) {
  __shared__ uint32_t kbuf[4][24][64];   // d-pairs x s x lane (24 KiB), reused for V
  const int ntile = blockIdx.x, h = blockIdx.y;
  const int n0 = ntile * 64;
  const int lane = threadIdx.x & 63, slot = threadIdx.x >> 6;
  const int t0 = slot * 3;
  const size_t baseq = (size_t)(h * 64) * JTOT + n0 + lane;
  const size_t basek = (size_t)(512 + h * 64) * JTOT + n0 + lane;
  const size_t basev = (size_t)(1024 + h * 64) * JTOT + n0 + lane;

  float S[3][24];
#pragma unroll
  for (int a = 0; a < 3; ++a)
#pragma unroll
    for (int s = 0; s < 24; ++s) S[a][s] = 0.f;

  uint32_t kp[12], qp[12];

  // prologue loads: chunk 0
#pragma unroll
  for (int dp = 0; dp < 4; ++dp)
#pragma unroll
    for (int a = 0; a < 3; ++a) {
      uint32_t klo = qkv[basek + (size_t)(2 * dp) * JTOT + (t0 + a) * NN];
      uint32_t khi = qkv[basek + (size_t)(2 * dp + 1) * JTOT + (t0 + a) * NN];
      kp[dp * 3 + a] = klo | (khi << 16);
      uint32_t qlo = qkv[baseq + (size_t)(2 * dp) * JTOT + (t0 + a) * NN];
      uint32_t qhi = qkv[baseq + (size_t)(2 * dp + 1) * JTOT + (t0 + a) * NN];
      qp[dp * 3 + a] = qlo | (qhi << 16);
    }

  for (int c = 0; c < 8; ++c) {
    const int dc = c * 8;
    // write current chunk K to LDS
#pragma unroll
    for (int dp = 0; dp < 4; ++dp)
#pragma unroll
      for (int a = 0; a < 3; ++a)
        kbuf[dp][t0 + a][lane] = kp[dp * 3 + a];
    // unpack this chunk's q
    float qf[3][8];
#pragma unroll
    for (int dp = 0; dp < 4; ++dp)
#pragma unroll
      for (int a = 0; a < 3; ++a) {
        qf[a][2 * dp]     = bflo(qp[dp * 3 + a]);
        qf[a][2 * dp + 1] = bfhi(qp[dp * 3 + a]);
      }
    // prefetch next chunk
    if (c < 7) {
      const int dn = dc + 8;
#pragma unroll
      for (int dp = 0; dp < 4; ++dp)
#pragma unroll
        for (int a = 0; a < 3; ++a) {
          uint32_t klo = qkv[basek + (size_t)(dn + 2 * dp) * JTOT + (t0 + a) * NN];
          uint32_t khi = qkv[basek + (size_t)(dn + 2 * dp + 1) * JTOT + (t0 + a) * NN];
          kp[dp * 3 + a] = klo | (khi << 16);
          uint32_t qlo = qkv[baseq + (size_t)(dn + 2 * dp) * JTOT + (t0 + a) * NN];
          uint32_t qhi = qkv[baseq + (size_t)(dn + 2 * dp + 1) * JTOT + (t0 + a) * NN];
          qp[dp * 3 + a] = qlo | (qhi << 16);
        }
    }
    __syncthreads();
#pragma unroll
    for (int dp = 0; dp < 4; ++dp) {
#pragma unroll
      for (int s = 0; s < 24; ++s) {
        uint32_t kpr = kbuf[dp][s][lane];
        float k0 = bflo(kpr), k1 = bfhi(kpr);
        S[0][s] = fmaf(qf[0][2 * dp], k0, S[0][s]);
        S[0][s] = fmaf(qf[0][2 * dp + 1], k1, S[0][s]);
        S[1][s] = fmaf(qf[1][2 * dp], k0, S[1][s]);
        S[1][s] = fmaf(qf[1][2 * dp + 1], k1, S[1][s]);
        S[2][s] = fmaf(qf[2][2 * dp], k0, S[2][s]);
        S[2][s] = fmaf(qf[2][2 * dp + 1], k1, S[2][s]);
      }
    }
    __syncthreads();
  }

  // prefetch V chunk 0 (hide under softmax)
#pragma unroll
  for (int dp = 0; dp < 4; ++dp)
#pragma unroll
    for (int a = 0; a < 3; ++a) {
      uint32_t vlo = qkv[basev + (size_t)(2 * dp) * JTOT + (t0 + a) * NN];
      uint32_t vhi = qkv[basev + (size_t)(2 * dp + 1) * JTOT + (t0 + a) * NN];
      kp[dp * 3 + a] = vlo | (vhi << 16);
    }

  // softmax on S (scale 1/sqrt(64) = 0.125)
#pragma unroll
  for (int a = 0; a < 3; ++a) {
    float mx = S[a][0];
#pragma unroll
    for (int s = 1; s < 24; ++s) mx = fmaxf(mx, S[a][s]);
    float sum = 0.f;
#pragma unroll
    for (int s = 0; s < 24; ++s) {
      float e = __expf((S[a][s] - mx) * 0.125f);
      S[a][s] = e; sum += e;
    }
    float inv = 1.f / sum;
#pragma unroll
    for (int s = 0; s < 24; ++s) S[a][s] *= inv;
  }

  for (int c = 0; c < 8; ++c) {
    const int dc = c * 8;
#pragma unroll
    for (int dp = 0; dp < 4; ++dp)
#pragma unroll
      for (int a = 0; a < 3; ++a)
        kbuf[dp][t0 + a][lane] = kp[dp * 3 + a];
    if (c < 7) {
      const int dn = dc + 8;
#pragma unroll
      for (int dp = 0; dp < 4; ++dp)
#pragma unroll
        for (int a = 0; a < 3; ++a) {
          uint32_t vlo = qkv[basev + (size_t)(dn + 2 * dp) * JTOT + (t0 + a) * NN];
          uint32_t vhi = qkv[basev + (size_t)(dn + 2 * dp + 1) * JTOT + (t0 + a) * NN];
          kp[dp * 3 + a] = vlo | (vhi << 16);
        }
    }
    __syncthreads();
    float o[3][8];
#pragma unroll
    for (int a = 0; a < 3; ++a)
#pragma unroll
      for (int d = 0; d < 8; ++d) o[a][d] = 0.f;
#pragma unroll
    for (int dp = 0; dp < 4; ++dp) {
#pragma unroll
      for (int s = 0; s < 24; ++s) {
        uint32_t vpr = kbuf[dp][s][lane];
        float v0 = bflo(vpr), v1 = bfhi(vpr);
        o[0][2 * dp]     = fmaf(S[0][s], v0, o[0][2 * dp]);
        o[0][2 * dp + 1] = fmaf(S[0][s], v1, o[0][2 * dp + 1]);
        o[1][2 * dp]     = fmaf(S[1][s], v0, o[1][2 * dp]);
        o[1][2 * dp + 1] = fmaf(S[1][s], v1, o[1][2 * dp + 1]);
        o[2][2 * dp]     = fmaf(S[2][s], v0, o[2][2 * dp]);
        o[2][2 * dp + 1] = fmaf(S[2][s], v1, o[2][2 * dp + 1]);
      }
    }
    // store: kc = h*8 + c, j = (t0+a)*NN + n0 + lane -> 16B units, lanes contiguous
#pragma unroll
    for (int a = 0; a < 3; ++a) {
      uint4 w;
      w.x = pkbf(o[a][0], o[a][1]);
      w.y = pkbf(o[a][2], o[a][3]);
      w.z = pkbf(o[a][4], o[a][5]);
      w.w = pkbf(o[a][6], o[a][7]);
      size_t unit = (size_t)(h * 8 + c) * JTOT + (size_t)(t0 + a) * NN + n0 + lane;
      *reinterpret_cast<uint4*>(&aoC[unit * 8]) = w;
    }
    __syncthreads();
  }
}

extern "C" void kernel_launch(void* const* d_in, const int* in_sizes, int n_in,
                              void* d_out, int out_size, void* d_ws, size_t ws_size,
                              hipStream_t stream) {
  (void)in_sizes; (void)n_in; (void)out_size; (void)ws_size;
  const float* x     = (const float*)d_in[0];
  const float* gnw   = (const float*)d_in[1];
  const float* gnb   = (const float*)d_in[2];
  const float* qkvw  = (const float*)d_in[3];
  const float* qkvb  = (const float*)d_in[4];
  const float* projw = (const float*)d_in[5];
  const float* projb = (const float*)d_in[6];
  float* out = (float*)d_out;
  char* ws = (char*)d_ws;

  unsigned short* qkvw_bf = (unsigned short*)(ws);                    // 1,572,864 B
  unsigned short* projw_bf = (unsigned short*)(ws + 1572864);         //   524,288 B
  float* mean = (float*)(ws + 2097152);                               //   524,288 B
  float* rstd = (float*)(ws + 2621440);                               //   524,288 B
  unsigned short* xn  = (unsigned short*)(ws + 3145728);              // 100,663,296 B (also attnout chunked)
  unsigned short* qkv = (unsigned short*)(ws + 3145728 + 100663296);  // 301,989,888 B

  k_cvt<<<dim3(3072), dim3(256), 0, stream>>>(qkvw, projw, qkvw_bf, projw_bf);
  k_stats<<<dim3(2048), dim3(256), 0, stream>>>(x, mean, rstd);
  k_norm<<<dim3(1536), dim3(256), 0, stream>>>(x, mean, rstd, gnw, gnb, xn);
  k_gemm<0><<<dim3(768, 12), dim3(256), 0, stream>>>(qkvw_bf, xn, qkvb, qkv, nullptr, nullptr);
  k_attn<<<dim3(64, 8), dim3(512), 0, stream>>>(qkv, xn);  // chunked attnout overwrites xn
  k_gemm<1><<<dim3(768, 4), dim3(256), 0, stream>>>(projw_bf, xn, projb, nullptr, x, out);
}

// Round 4
// 816.287 us; speedup vs baseline: 1.4007x; 1.0038x over previous
//
#include <hip/hip_runtime.h>
#include <hip/hip_bf16.h>
#include <stdint.h>

#define C_    512
#define T_    24
#define HWSZ  1024
#define NN    4096
#define JTOT  98304   // T_*NN
#define EPSV  1e-5f

typedef short short8 __attribute__((ext_vector_type(8)));
typedef float f32x4 __attribute__((ext_vector_type(4)));

typedef __attribute__((address_space(1))) const uint32_t glob_u32;
typedef __attribute__((address_space(3))) uint32_t lds_u32;

__device__ __forceinline__ unsigned short f2bf(float f) {
  union { float f; unsigned u; } v; v.f = f;
  unsigned r = v.u + 0x7fffu + ((v.u >> 16) & 1u);
  return (unsigned short)(r >> 16);
}
__device__ __forceinline__ float bf2f(unsigned short b) {
  union { unsigned u; float f; } v; v.u = ((unsigned)b) << 16;
  return v.f;
}
__device__ __forceinline__ float bflo(uint32_t u) {
  union { unsigned u; float f; } v; v.u = u << 16; return v.f;
}
__device__ __forceinline__ float bfhi(uint32_t u) {
  union { unsigned u; float f; } v; v.u = u & 0xffff0000u; return v.f;
}
__device__ __forceinline__ uint32_t pkbf(float a, float b) {
  return (uint32_t)f2bf(a) | ((uint32_t)f2bf(b) << 16);
}

__device__ __forceinline__ void gload_lds16(const void* g, void* l) {
  __builtin_amdgcn_global_load_lds((glob_u32*)g, (lds_u32*)l, 16, 0, 0);
}

// ---------------- K0: weight f32 -> bf16 ----------------
__global__ void k_cvt(const float* __restrict__ qkvw, const float* __restrict__ projw,
                      unsigned short* __restrict__ qkvw_bf, unsigned short* __restrict__ projw_bf) {
  int i = blockIdx.x * 256 + threadIdx.x;
  if (i < 786432) qkvw_bf[i] = f2bf(qkvw[i]);
  if (i < 262144) projw_bf[i] = f2bf(projw[i]);
}

// ---------------- K1a: GroupNorm stats ----------------
__global__ __launch_bounds__(256) void k_stats(const float* __restrict__ x,
                                               float* __restrict__ mean, float* __restrict__ rstd) {
  int bid = blockIdx.x;
  int g = bid & 31, hwt = (bid >> 5) & 15, b = bid >> 9;
  int tid = threadIdx.x, lane = tid & 63, grp = tid >> 6;
  int hw = hwt * 64 + lane;
  float s = 0.f, sq = 0.f;
  for (int ct = grp; ct < 384; ct += 4) {
    int c = g * 16 + ct / 24;
    int t = ct % 24;
    float v = x[((size_t)((b * 512 + c) * 24 + t) << 10) + hw];
    s += v; sq += v * v;
  }
  __shared__ float ls[4][64], lq[4][64];
  ls[grp][lane] = s; lq[grp][lane] = sq;
  __syncthreads();
  if (tid < 64) {
    float S = ls[0][tid] + ls[1][tid] + ls[2][tid] + ls[3][tid];
    float Q = lq[0][tid] + lq[1][tid] + lq[2][tid] + lq[3][tid];
    float m = S * (1.f / 384.f);
    float var = Q * (1.f / 384.f) - m * m;
    int n = b * HWSZ + hwt * 64 + tid;
    mean[n * 32 + g] = m;
    rstd[n * 32 + g] = rsqrtf(var + EPSV);
  }
}

// ---------------- K1b: normalize + transpose to Xn[j][c] bf16 ----------------
__global__ __launch_bounds__(256) void k_norm(const float* __restrict__ x,
                                              const float* __restrict__ mean, const float* __restrict__ rstd,
                                              const float* __restrict__ gnw, const float* __restrict__ gnb,
                                              unsigned short* __restrict__ xn) {
  __shared__ unsigned short xs[C_][66];
  int bid = blockIdx.x;
  int hwt = bid & 15, tb = bid >> 4;
  int t = tb % 24, b = tb / 24;
  int tid = threadIdx.x, lane = tid & 63, grp = tid >> 6;
  int hw = hwt * 64 + lane;
  int n = b * HWSZ + hw;
  for (int c = grp; c < C_; c += 4) {
    float v = x[((size_t)((b * 512 + c) * 24 + t) << 10) + hw];
    int g = c >> 4;
    float xv = (v - mean[n * 32 + g]) * rstd[n * 32 + g] * gnw[c] + gnb[c];
    xs[c][lane] = f2bf(xv);
  }
  __syncthreads();
  int w = grp, l = lane;
  for (int p = 0; p < 16; ++p) {
    int nl = p * 4 + w;
    size_t j = (size_t)t * NN + b * HWSZ + hwt * 64 + nl;
    unsigned short tmp[8] __attribute__((aligned(16)));
#pragma unroll
    for (int m = 0; m < 8; ++m) tmp[m] = xs[l * 8 + m][nl];
    *reinterpret_cast<uint4*>(&xn[j * C_ + l * 8]) = *reinterpret_cast<const uint4*>(tmp);
  }
}

// ---------------- K2/K4: bf16 MFMA GEMM (gemm_bt; m97 structure) ----------------
// 1D grid with bijective XCD swizzle; mt varies fastest within an XCD chunk so
// blocks sharing a B-panel are temporally adjacent on one XCD's L2.
// MODE0: B = [JTOT][512] row-major, nmt=12.  MODE1: B = chunked [64 kc][JTOT][8], nmt=4.
template <int MODE>
__global__ __launch_bounds__(256, 3) void k_gemm(
    const unsigned short* __restrict__ A,   // [M][512] bf16
    const unsigned short* __restrict__ B,
    const float* __restrict__ bias,         // [M]
    unsigned short* __restrict__ outb,      // MODE0: [M][JTOT] bf16
    const float* __restrict__ xres,         // MODE1: residual source
    float* __restrict__ outf) {             // MODE1: final f32 out
  __shared__ __attribute__((aligned(16))) unsigned short As[128 * 64];
  __shared__ __attribute__((aligned(16))) unsigned short Bs[128 * 64];
  const int NMT = (MODE == 0) ? 12 : 4;
  const int bid = blockIdx.x;
  const int cpx = gridDim.x >> 3;
  const int lid = (bid & 7) * cpx + (bid >> 3);
  const int mt = lid % NMT, jt = lid / NMT;
  const int j0 = jt * 128, m0 = mt * 128;
  const int tid = threadIdx.x;
  const int wave = tid >> 6, lane = tid & 63;
  const int l16 = lane & 15, lqq = lane >> 4;
  const int wm = wave >> 1, wn = wave & 1;
  const int srow = lane >> 3, sseg = lane & 7;

  f32x4 acc[4][4];
#pragma unroll
  for (int i = 0; i < 4; ++i)
#pragma unroll
    for (int j = 0; j < 4; ++j) acc[i][j] = {0.f, 0.f, 0.f, 0.f};

  for (int kt = 0; kt < 512; kt += 64) {
#pragma unroll
    for (int i = 0; i < 4; ++i) {
      const int chunk = i * 4 + wave;
      const int r = chunk * 8 + srow;
      gload_lds16(A + ((size_t)(m0 + r) * 512 + kt + sseg * 8), &As[chunk * 512]);
    }
    if (MODE == 0) {
#pragma unroll
      for (int i = 0; i < 4; ++i) {
        const int chunk = i * 4 + wave;
        const int r = chunk * 8 + srow;
        gload_lds16(B + ((size_t)(j0 + r) * 512 + kt + sseg * 8), &Bs[chunk * 512]);
      }
    } else {
#pragma unroll
      for (int p = 0; p < 4; ++p) {
        const int u = p * 256 + tid;
        const int kc = u >> 7, jr = u & 127;
        gload_lds16(B + ((size_t)((kt >> 3) + kc) * JTOT + (j0 + jr)) * 8, &Bs[(size_t)u * 8]);
      }
    }
    __syncthreads();
#pragma unroll
    for (int ks = 0; ks < 2; ++ks) {
      short8 af[4], bfr[4];
#pragma unroll
      for (int i = 0; i < 4; ++i)
        af[i] = *reinterpret_cast<const short8*>(&As[(wm * 64 + i * 16 + l16) * 64 + ks * 32 + lqq * 8]);
#pragma unroll
      for (int i = 0; i < 4; ++i) {
        if (MODE == 0)
          bfr[i] = *reinterpret_cast<const short8*>(&Bs[(wn * 64 + i * 16 + l16) * 64 + ks * 32 + lqq * 8]);
        else
          bfr[i] = *reinterpret_cast<const short8*>(&Bs[(((ks * 4 + lqq) * 128) + wn * 64 + i * 16 + l16) * 8]);
      }
#pragma unroll
      for (int mi = 0; mi < 4; ++mi)
#pragma unroll
        for (int ni = 0; ni < 4; ++ni)
          acc[mi][ni] = __builtin_amdgcn_mfma_f32_16x16x32_bf16(af[mi], bfr[ni], acc[mi][ni], 0, 0, 0);
    }
    __syncthreads();
  }

#pragma unroll
  for (int mi = 0; mi < 4; ++mi) {
#pragma unroll
    for (int ni = 0; ni < 4; ++ni) {
      const int dbase = m0 + wm * 64 + mi * 16 + lqq * 4;
      const int jj = j0 + wn * 64 + ni * 16 + l16;
      if (MODE == 0) {
#pragma unroll
        for (int r = 0; r < 4; ++r) {
          float v = acc[mi][ni][r] + bias[dbase + r];
          outb[(size_t)(dbase + r) * JTOT + jj] = f2bf(v);
        }
      } else {
        const int t = jj >> 12, n = jj & 4095;
        const int b = n >> 10, hw = n & 1023;
#pragma unroll
        for (int r = 0; r < 4; ++r) {
          size_t o = (((size_t)(b * 512 + dbase + r) * 24 + t) << 10) + hw;
          outf[o] = xres[o] + acc[mi][ni][r] + bias[dbase + r];
        }
      }
    }
  }
}

// ---------------- K3: attention (VALU f32, lane = n, d-pair packed LDS) ----------------
__global__ __launch_bounds__(512) void k_attn(const unsigned short* __restrict__ qkv,
                                              unsigned short* __restrict__ aoC) {
  __shared__ uint32_t kbuf[4][24][64];
  const int ntile = blockIdx.x, h = blockIdx.y;
  const int n0 = ntile * 64;
  const int lane = threadIdx.x & 63, slot = threadIdx.x >> 6;
  const int t0 = slot * 3;
  const size_t baseq = (size_t)(h * 64) * JTOT + n0 + lane;
  const size_t basek = (size_t)(512 + h * 64) * JTOT + n0 + lane;
  const size_t basev = (size_t)(1024 + h * 64) * JTOT + n0 + lane;

  float S[3][24];
#pragma unroll
  for (int a = 0; a < 3; ++a)
#pragma unroll
    for (int s = 0; s < 24; ++s) S[a][s] = 0.f;

  uint32_t kp[12], qp[12];

#pragma unroll
  for (int dp = 0; dp < 4; ++dp)
#pragma unroll
    for (int a = 0; a < 3; ++a) {
      uint32_t klo = qkv[basek + (size_t)(2 * dp) * JTOT + (t0 + a) * NN];
      uint32_t khi = qkv[basek + (size_t)(2 * dp + 1) * JTOT + (t0 + a) * NN];
      kp[dp * 3 + a] = klo | (khi << 16);
      uint32_t qlo = qkv[baseq + (size_t)(2 * dp) * JTOT + (t0 + a) * NN];
      uint32_t qhi = qkv[baseq + (size_t)(2 * dp + 1) * JTOT + (t0 + a) * NN];
      qp[dp * 3 + a] = qlo | (qhi << 16);
    }

  for (int c = 0; c < 8; ++c) {
    const int dc = c * 8;
#pragma unroll
    for (int dp = 0; dp < 4; ++dp)
#pragma unroll
      for (int a = 0; a < 3; ++a)
        kbuf[dp][t0 + a][lane] = kp[dp * 3 + a];
    float qf[3][8];
#pragma unroll
    for (int dp = 0; dp < 4; ++dp)
#pragma unroll
      for (int a = 0; a < 3; ++a) {
        qf[a][2 * dp]     = bflo(qp[dp * 3 + a]);
        qf[a][2 * dp + 1] = bfhi(qp[dp * 3 + a]);
      }
    if (c < 7) {
      const int dn = dc + 8;
#pragma unroll
      for (int dp = 0; dp < 4; ++dp)
#pragma unroll
        for (int a = 0; a < 3; ++a) {
          uint32_t klo = qkv[basek + (size_t)(dn + 2 * dp) * JTOT + (t0 + a) * NN];
          uint32_t khi = qkv[basek + (size_t)(dn + 2 * dp + 1) * JTOT + (t0 + a) * NN];
          kp[dp * 3 + a] = klo | (khi << 16);
          uint32_t qlo = qkv[baseq + (size_t)(dn + 2 * dp) * JTOT + (t0 + a) * NN];
          uint32_t qhi = qkv[baseq + (size_t)(dn + 2 * dp + 1) * JTOT + (t0 + a) * NN];
          qp[dp * 3 + a] = qlo | (qhi << 16);
        }
    }
    __syncthreads();
#pragma unroll
    for (int dp = 0; dp < 4; ++dp) {
#pragma unroll
      for (int s = 0; s < 24; ++s) {
        uint32_t kpr = kbuf[dp][s][lane];
        float k0 = bflo(kpr), k1 = bfhi(kpr);
        S[0][s] = fmaf(qf[0][2 * dp], k0, S[0][s]);
        S[0][s] = fmaf(qf[0][2 * dp + 1], k1, S[0][s]);
        S[1][s] = fmaf(qf[1][2 * dp], k0, S[1][s]);
        S[1][s] = fmaf(qf[1][2 * dp + 1], k1, S[1][s]);
        S[2][s] = fmaf(qf[2][2 * dp], k0, S[2][s]);
        S[2][s] = fmaf(qf[2][2 * dp + 1], k1, S[2][s]);
      }
    }
    __syncthreads();
  }

#pragma unroll
  for (int dp = 0; dp < 4; ++dp)
#pragma unroll
    for (int a = 0; a < 3; ++a) {
      uint32_t vlo = qkv[basev + (size_t)(2 * dp) * JTOT + (t0 + a) * NN];
      uint32_t vhi = qkv[basev + (size_t)(2 * dp + 1) * JTOT + (t0 + a) * NN];
      kp[dp * 3 + a] = vlo | (vhi << 16);
    }

#pragma unroll
  for (int a = 0; a < 3; ++a) {
    float mx = S[a][0];
#pragma unroll
    for (int s = 1; s < 24; ++s) mx = fmaxf(mx, S[a][s]);
    float sum = 0.f;
#pragma unroll
    for (int s = 0; s < 24; ++s) {
      float e = __expf((S[a][s] - mx) * 0.125f);
      S[a][s] = e; sum += e;
    }
    float inv = 1.f / sum;
#pragma unroll
    for (int s = 0; s < 24; ++s) S[a][s] *= inv;
  }

  for (int c = 0; c < 8; ++c) {
    const int dc = c * 8;
#pragma unroll
    for (int dp = 0; dp < 4; ++dp)
#pragma unroll
      for (int a = 0; a < 3; ++a)
        kbuf[dp][t0 + a][lane] = kp[dp * 3 + a];
    if (c < 7) {
      const int dn = dc + 8;
#pragma unroll
      for (int dp = 0; dp < 4; ++dp)
#pragma unroll
        for (int a = 0; a < 3; ++a) {
          uint32_t vlo = qkv[basev + (size_t)(dn + 2 * dp) * JTOT + (t0 + a) * NN];
          uint32_t vhi = qkv[basev + (size_t)(dn + 2 * dp + 1) * JTOT + (t0 + a) * NN];
          kp[dp * 3 + a] = vlo | (vhi << 16);
        }
    }
    __syncthreads();
    float o[3][8];
#pragma unroll
    for (int a = 0; a < 3; ++a)
#pragma unroll
      for (int d = 0; d < 8; ++d) o[a][d] = 0.f;
#pragma unroll
    for (int dp = 0; dp < 4; ++dp) {
#pragma unroll
      for (int s = 0; s < 24; ++s) {
        uint32_t vpr = kbuf[dp][s][lane];
        float v0 = bflo(vpr), v1 = bfhi(vpr);
        o[0][2 * dp]     = fmaf(S[0][s], v0, o[0][2 * dp]);
        o[0][2 * dp + 1] = fmaf(S[0][s], v1, o[0][2 * dp + 1]);
        o[1][2 * dp]     = fmaf(S[1][s], v0, o[1][2 * dp]);
        o[1][2 * dp + 1] = fmaf(S[1][s], v1, o[1][2 * dp + 1]);
        o[2][2 * dp]     = fmaf(S[2][s], v0, o[2][2 * dp]);
        o[2][2 * dp + 1] = fmaf(S[2][s], v1, o[2][2 * dp + 1]);
      }
    }
#pragma unroll
    for (int a = 0; a < 3; ++a) {
      uint4 w;
      w.x = pkbf(o[a][0], o[a][1]);
      w.y = pkbf(o[a][2], o[a][3]);
      w.z = pkbf(o[a][4], o[a][5]);
      w.w = pkbf(o[a][6], o[a][7]);
      size_t unit = (size_t)(h * 8 + c) * JTOT + (size_t)(t0 + a) * NN + n0 + lane;
      *reinterpret_cast<uint4*>(&aoC[unit * 8]) = w;
    }
    __syncthreads();
  }
}

extern "C" void kernel_launch(void* const* d_in, const int* in_sizes, int n_in,
                              void* d_out, int out_size, void* d_ws, size_t ws_size,
                              hipStream_t stream) {
  (void)in_sizes; (void)n_in; (void)out_size; (void)ws_size;
  const float* x     = (const float*)d_in[0];
  const float* gnw   = (const float*)d_in[1];
  const float* gnb   = (const float*)d_in[2];
  const float* qkvw  = (const float*)d_in[3];
  const float* qkvb  = (const float*)d_in[4];
  const float* projw = (const float*)d_in[5];
  const float* projb = (const float*)d_in[6];
  float* out = (float*)d_out;
  char* ws = (char*)d_ws;

  unsigned short* qkvw_bf = (unsigned short*)(ws);                    // 1,572,864 B
  unsigned short* projw_bf = (unsigned short*)(ws + 1572864);         //   524,288 B
  float* mean = (float*)(ws + 2097152);                               //   524,288 B
  float* rstd = (float*)(ws + 2621440);                               //   524,288 B
  unsigned short* xn  = (unsigned short*)(ws + 3145728);              // 100,663,296 B (also attnout chunked)
  unsigned short* qkv = (unsigned short*)(ws + 3145728 + 100663296);  // 301,989,888 B

  k_cvt<<<dim3(3072), dim3(256), 0, stream>>>(qkvw, projw, qkvw_bf, projw_bf);
  k_stats<<<dim3(2048), dim3(256), 0, stream>>>(x, mean, rstd);
  k_norm<<<dim3(1536), dim3(256), 0, stream>>>(x, mean, rstd, gnw, gnb, xn);
  k_gemm<0><<<dim3(9216), dim3(256), 0, stream>>>(qkvw_bf, xn, qkvb, qkv, nullptr, nullptr);
  k_attn<<<dim3(64, 8), dim3(512), 0, stream>>>(qkv, xn);  // chunked attnout overwrites xn
  k_gemm<1><<<dim3(3072), dim3(256), 0, stream>>>(projw_bf, xn, projb, nullptr, x, out);
}

// Round 5
// 761.777 us; speedup vs baseline: 1.5009x; 1.0716x over previous
//
#include <hip/hip_runtime.h>
#include <hip/hip_bf16.h>
#include <stdint.h>

#define C_    512
#define T_    24
#define HWSZ  1024
#define NN    4096
#define JTOT  98304   // T_*NN
#define EPSV  1e-5f

typedef short short8 __attribute__((ext_vector_type(8)));
typedef float f32x4 __attribute__((ext_vector_type(4)));

typedef __attribute__((address_space(1))) const uint32_t glob_u32;
typedef __attribute__((address_space(3))) uint32_t lds_u32;

__device__ __forceinline__ unsigned short f2bf(float f) {
  union { float f; unsigned u; } v; v.f = f;
  unsigned r = v.u + 0x7fffu + ((v.u >> 16) & 1u);
  return (unsigned short)(r >> 16);
}
__device__ __forceinline__ float bf2f(unsigned short b) {
  union { unsigned u; float f; } v; v.u = ((unsigned)b) << 16;
  return v.f;
}
__device__ __forceinline__ float bflo(uint32_t u) {
  union { unsigned u; float f; } v; v.u = u << 16; return v.f;
}
__device__ __forceinline__ float bfhi(uint32_t u) {
  union { unsigned u; float f; } v; v.u = u & 0xffff0000u; return v.f;
}
__device__ __forceinline__ uint32_t pkbf(float a, float b) {
  return (uint32_t)f2bf(a) | ((uint32_t)f2bf(b) << 16);
}

__device__ __forceinline__ void gload_lds16(const void* g, void* l) {
  __builtin_amdgcn_global_load_lds((glob_u32*)g, (lds_u32*)l, 16, 0, 0);
}

// ---------------- K0: weight f32 -> bf16 ----------------
__global__ void k_cvt(const float* __restrict__ qkvw, const float* __restrict__ projw,
                      unsigned short* __restrict__ qkvw_bf, unsigned short* __restrict__ projw_bf) {
  int i = blockIdx.x * 256 + threadIdx.x;
  if (i < 786432) qkvw_bf[i] = f2bf(qkvw[i]);
  if (i < 262144) projw_bf[i] = f2bf(projw[i]);
}

// ---------------- K1a: GroupNorm stats ----------------
__global__ __launch_bounds__(256) void k_stats(const float* __restrict__ x,
                                               float* __restrict__ mean, float* __restrict__ rstd) {
  int bid = blockIdx.x;
  int g = bid & 31, hwt = (bid >> 5) & 15, b = bid >> 9;
  int tid = threadIdx.x, lane = tid & 63, grp = tid >> 6;
  int hw = hwt * 64 + lane;
  float s = 0.f, sq = 0.f;
  for (int ct = grp; ct < 384; ct += 4) {
    int c = g * 16 + ct / 24;
    int t = ct % 24;
    float v = x[((size_t)((b * 512 + c) * 24 + t) << 10) + hw];
    s += v; sq += v * v;
  }
  __shared__ float ls[4][64], lq[4][64];
  ls[grp][lane] = s; lq[grp][lane] = sq;
  __syncthreads();
  if (tid < 64) {
    float S = ls[0][tid] + ls[1][tid] + ls[2][tid] + ls[3][tid];
    float Q = lq[0][tid] + lq[1][tid] + lq[2][tid] + lq[3][tid];
    float m = S * (1.f / 384.f);
    float var = Q * (1.f / 384.f) - m * m;
    int n = b * HWSZ + hwt * 64 + tid;
    mean[n * 32 + g] = m;
    rstd[n * 32 + g] = rsqrtf(var + EPSV);
  }
}

// ---------------- K1b: normalize + transpose to Xn[j][c] bf16 ----------------
__global__ __launch_bounds__(256) void k_norm(const float* __restrict__ x,
                                              const float* __restrict__ mean, const float* __restrict__ rstd,
                                              const float* __restrict__ gnw, const float* __restrict__ gnb,
                                              unsigned short* __restrict__ xn) {
  __shared__ unsigned short xs[C_][66];
  int bid = blockIdx.x;
  int hwt = bid & 15, tb = bid >> 4;
  int t = tb % 24, b = tb / 24;
  int tid = threadIdx.x, lane = tid & 63, grp = tid >> 6;
  int hw = hwt * 64 + lane;
  int n = b * HWSZ + hw;
  for (int c = grp; c < C_; c += 4) {
    float v = x[((size_t)((b * 512 + c) * 24 + t) << 10) + hw];
    int g = c >> 4;
    float xv = (v - mean[n * 32 + g]) * rstd[n * 32 + g] * gnw[c] + gnb[c];
    xs[c][lane] = f2bf(xv);
  }
  __syncthreads();
  int w = grp, l = lane;
  for (int p = 0; p < 16; ++p) {
    int nl = p * 4 + w;
    size_t j = (size_t)t * NN + b * HWSZ + hwt * 64 + nl;
    unsigned short tmp[8] __attribute__((aligned(16)));
#pragma unroll
    for (int m = 0; m < 8; ++m) tmp[m] = xs[l * 8 + m][nl];
    *reinterpret_cast<uint4*>(&xn[j * C_ + l * 8]) = *reinterpret_cast<const uint4*>(tmp);
  }
}

// ---------------- K2: 256x256 8-phase bf16 MFMA GEMM (QKV) ----------------
// C[m][j] = sum_k A[m][k]*B[j][k] + bias[m], out bf16 [M=1536][JTOT].
// 8 waves (2M x 4N), BK=64, NT=8 K-tiles, 128 KiB dbuf LDS, counted vmcnt,
// per-row XOR slot swizzle (pre-swizzled global source + swizzled ds_read).
#define STAGE8(mat, half, tile, Gptr, row0)                                           \
  {                                                                                   \
    unsigned short* _l = &lds[(((tile) & 1) * 2 + (mat))][half][(w * 2) * 512];       \
    const unsigned short* _g = (Gptr) +                                               \
        (size_t)((row0) + (half) * 128 + (w * 2) * 8 + srow) * 512 +                  \
        (tile) * 64 + sslot * 8;                                                      \
    gload_lds16(_g, _l);                                                              \
    gload_lds16(_g + 8 * 512, _l + 512);                                              \
  }

__global__ __launch_bounds__(512, 2) void k_gemm8(
    const unsigned short* __restrict__ A,   // [1536][512] bf16
    const unsigned short* __restrict__ B,   // [JTOT][512] bf16
    const float* __restrict__ bias,         // [1536]
    unsigned short* __restrict__ outb) {    // [1536][JTOT] bf16
  __shared__ __attribute__((aligned(16))) unsigned short lds[4][2][8192]; // [buf*2+mat][half][128*64]
  const int bid = blockIdx.x;
  const int cpx = 2304 >> 3;  // grid 2304 = 8 * 288, bijective
  const int lid = (bid & 7) * cpx + (bid >> 3);
  const int mt = lid % 6, jt = lid / 6;
  const int m0 = mt * 256, j0 = jt * 256;
  const int tid = threadIdx.x;
  const int w = tid >> 6, lane = tid & 63;
  const int l16 = lane & 15, lqq = lane >> 4;
  const int wm = w >> 2, wn = w & 3;
  const int srow = lane >> 3;
  const int sslot = (lane & 7) ^ srow;
  // swizzled k-offsets for ds_read (elements): slot = (ks*4+lqq) ^ (l16&7)
  const int k0off = l16 * 64 + ((lqq ^ (l16 & 7)) * 8);
  const int k1off = l16 * 64 + (((lqq + 4) ^ (l16 & 7)) * 8);

  f32x4 acc[8][4];
#pragma unroll
  for (int i = 0; i < 8; ++i)
#pragma unroll
    for (int j = 0; j < 4; ++j) acc[i][j] = {0.f, 0.f, 0.f, 0.f};

  // prologue: tile0 all 4 halves + tile1 {A0,A1,B0} -> 14 loads, wait tile0 (6 left)
  STAGE8(0, 0, 0, A, m0); STAGE8(0, 1, 0, A, m0);
  STAGE8(1, 0, 0, B, j0); STAGE8(1, 1, 0, B, j0);
  STAGE8(0, 0, 1, A, m0); STAGE8(0, 1, 1, A, m0);
  STAGE8(1, 0, 1, B, j0);
  asm volatile("s_waitcnt vmcnt(6)" ::: "memory");
  __builtin_amdgcn_s_barrier();

  for (int t = 0; t < 8; ++t) {
    const int buf = t & 1;
    const unsigned short* Ab = &lds[buf * 2 + 0][wm][0];
    const unsigned short* Bb = &lds[buf * 2 + 1][wn >> 1][(wn & 1) * 4096];
    short8 a[8][2], bb[4][2];
    // ---- phase 1: read all A frags + B c0-1; stage B1[t+1]; MFMA q(r0-3,c0-1)
#pragma unroll
    for (int rr = 0; rr < 8; ++rr) {
      a[rr][0] = *reinterpret_cast<const short8*>(Ab + rr * 1024 + k0off);
      a[rr][1] = *reinterpret_cast<const short8*>(Ab + rr * 1024 + k1off);
    }
#pragma unroll
    for (int cc = 0; cc < 2; ++cc) {
      bb[cc][0] = *reinterpret_cast<const short8*>(Bb + cc * 1024 + k0off);
      bb[cc][1] = *reinterpret_cast<const short8*>(Bb + cc * 1024 + k1off);
    }
    if (t < 7) STAGE8(1, 1, t + 1, B, j0);
    asm volatile("" ::: "memory");
    __builtin_amdgcn_s_barrier();
    asm volatile("s_waitcnt lgkmcnt(0)" ::: "memory");
    __builtin_amdgcn_sched_barrier(0);
    __builtin_amdgcn_s_setprio(1);
#pragma unroll
    for (int rr = 0; rr < 4; ++rr)
#pragma unroll
      for (int cc = 0; cc < 2; ++cc) {
        acc[rr][cc] = __builtin_amdgcn_mfma_f32_16x16x32_bf16(a[rr][0], bb[cc][0], acc[rr][cc], 0, 0, 0);
        acc[rr][cc] = __builtin_amdgcn_mfma_f32_16x16x32_bf16(a[rr][1], bb[cc][1], acc[rr][cc], 0, 0, 0);
      }
    __builtin_amdgcn_s_setprio(0);
    asm volatile("" ::: "memory");
    __builtin_amdgcn_s_barrier();
    // ---- phase 2: read B c2-3; stage A0[t+2]; MFMA q(r0-3,c2-3)
#pragma unroll
    for (int cc = 2; cc < 4; ++cc) {
      bb[cc][0] = *reinterpret_cast<const short8*>(Bb + cc * 1024 + k0off);
      bb[cc][1] = *reinterpret_cast<const short8*>(Bb + cc * 1024 + k1off);
    }
    if (t < 6) STAGE8(0, 0, t + 2, A, m0);
    asm volatile("" ::: "memory");
    __builtin_amdgcn_s_barrier();
    asm volatile("s_waitcnt lgkmcnt(0)" ::: "memory");
    __builtin_amdgcn_sched_barrier(0);
    __builtin_amdgcn_s_setprio(1);
#pragma unroll
    for (int rr = 0; rr < 4; ++rr)
#pragma unroll
      for (int cc = 2; cc < 4; ++cc) {
        acc[rr][cc] = __builtin_amdgcn_mfma_f32_16x16x32_bf16(a[rr][0], bb[cc][0], acc[rr][cc], 0, 0, 0);
        acc[rr][cc] = __builtin_amdgcn_mfma_f32_16x16x32_bf16(a[rr][1], bb[cc][1], acc[rr][cc], 0, 0, 0);
      }
    __builtin_amdgcn_s_setprio(0);
    asm volatile("" ::: "memory");
    __builtin_amdgcn_s_barrier();
    // ---- phase 3: stage A1[t+2]; MFMA q(r4-7,c0-1)
    if (t < 6) STAGE8(0, 1, t + 2, A, m0);
    asm volatile("" ::: "memory");
    __builtin_amdgcn_s_barrier();
    __builtin_amdgcn_s_setprio(1);
#pragma unroll
    for (int rr = 4; rr < 8; ++rr)
#pragma unroll
      for (int cc = 0; cc < 2; ++cc) {
        acc[rr][cc] = __builtin_amdgcn_mfma_f32_16x16x32_bf16(a[rr][0], bb[cc][0], acc[rr][cc], 0, 0, 0);
        acc[rr][cc] = __builtin_amdgcn_mfma_f32_16x16x32_bf16(a[rr][1], bb[cc][1], acc[rr][cc], 0, 0, 0);
      }
    __builtin_amdgcn_s_setprio(0);
    asm volatile("" ::: "memory");
    __builtin_amdgcn_s_barrier();
    // ---- phase 4: stage B0[t+2]; MFMA q(r4-7,c2-3); counted vmcnt; barrier
    if (t < 6) STAGE8(1, 0, t + 2, B, j0);
    asm volatile("" ::: "memory");
    __builtin_amdgcn_s_barrier();
    __builtin_amdgcn_s_setprio(1);
#pragma unroll
    for (int rr = 4; rr < 8; ++rr)
#pragma unroll
      for (int cc = 2; cc < 4; ++cc) {
        acc[rr][cc] = __builtin_amdgcn_mfma_f32_16x16x32_bf16(a[rr][0], bb[cc][0], acc[rr][cc], 0, 0, 0);
        acc[rr][cc] = __builtin_amdgcn_mfma_f32_16x16x32_bf16(a[rr][1], bb[cc][1], acc[rr][cc], 0, 0, 0);
      }
    __builtin_amdgcn_s_setprio(0);
    asm volatile("" ::: "memory");
    if (t < 6) {
      asm volatile("s_waitcnt vmcnt(6)" ::: "memory");
    } else if (t == 6) {
      asm volatile("s_waitcnt vmcnt(0)" ::: "memory");
    }
    __builtin_amdgcn_s_barrier();
  }

  // epilogue: bias + bf16 store
#pragma unroll
  for (int rr = 0; rr < 8; ++rr) {
#pragma unroll
    for (int cc = 0; cc < 4; ++cc) {
      const int row = m0 + wm * 128 + rr * 16 + lqq * 4;
      const int col = j0 + wn * 64 + cc * 16 + l16;
#pragma unroll
      for (int r = 0; r < 4; ++r) {
        float v = acc[rr][cc][r] + bias[row + r];
        outb[(size_t)(row + r) * JTOT + col] = f2bf(v);
      }
    }
  }
}

// ---------------- K4: bf16 MFMA GEMM (128^2, proj+residual) ----------------
// MODE1: B = chunked [64 kc][JTOT][8].
template <int MODE>
__global__ __launch_bounds__(256, 3) void k_gemm(
    const unsigned short* __restrict__ A,
    const unsigned short* __restrict__ B,
    const float* __restrict__ bias,
    unsigned short* __restrict__ outb,
    const float* __restrict__ xres,
    float* __restrict__ outf) {
  __shared__ __attribute__((aligned(16))) unsigned short As[128 * 64];
  __shared__ __attribute__((aligned(16))) unsigned short Bs[128 * 64];
  const int NMT = (MODE == 0) ? 12 : 4;
  const int bid = blockIdx.x;
  const int cpx = gridDim.x >> 3;
  const int lid = (bid & 7) * cpx + (bid >> 3);
  const int mt = lid % NMT, jt = lid / NMT;
  const int j0 = jt * 128, m0 = mt * 128;
  const int tid = threadIdx.x;
  const int wave = tid >> 6, lane = tid & 63;
  const int l16 = lane & 15, lqq = lane >> 4;
  const int wm = wave >> 1, wn = wave & 1;
  const int srow = lane >> 3, sseg = lane & 7;

  f32x4 acc[4][4];
#pragma unroll
  for (int i = 0; i < 4; ++i)
#pragma unroll
    for (int j = 0; j < 4; ++j) acc[i][j] = {0.f, 0.f, 0.f, 0.f};

  for (int kt = 0; kt < 512; kt += 64) {
#pragma unroll
    for (int i = 0; i < 4; ++i) {
      const int chunk = i * 4 + wave;
      const int r = chunk * 8 + srow;
      gload_lds16(A + ((size_t)(m0 + r) * 512 + kt + sseg * 8), &As[chunk * 512]);
    }
    if (MODE == 0) {
#pragma unroll
      for (int i = 0; i < 4; ++i) {
        const int chunk = i * 4 + wave;
        const int r = chunk * 8 + srow;
        gload_lds16(B + ((size_t)(j0 + r) * 512 + kt + sseg * 8), &Bs[chunk * 512]);
      }
    } else {
#pragma unroll
      for (int p = 0; p < 4; ++p) {
        const int u = p * 256 + tid;
        const int kc = u >> 7, jr = u & 127;
        gload_lds16(B + ((size_t)((kt >> 3) + kc) * JTOT + (j0 + jr)) * 8, &Bs[(size_t)u * 8]);
      }
    }
    __syncthreads();
#pragma unroll
    for (int ks = 0; ks < 2; ++ks) {
      short8 af[4], bfr[4];
#pragma unroll
      for (int i = 0; i < 4; ++i)
        af[i] = *reinterpret_cast<const short8*>(&As[(wm * 64 + i * 16 + l16) * 64 + ks * 32 + lqq * 8]);
#pragma unroll
      for (int i = 0; i < 4; ++i) {
        if (MODE == 0)
          bfr[i] = *reinterpret_cast<const short8*>(&Bs[(wn * 64 + i * 16 + l16) * 64 + ks * 32 + lqq * 8]);
        else
          bfr[i] = *reinterpret_cast<const short8*>(&Bs[(((ks * 4 + lqq) * 128) + wn * 64 + i * 16 + l16) * 8]);
      }
#pragma unroll
      for (int mi = 0; mi < 4; ++mi)
#pragma unroll
        for (int ni = 0; ni < 4; ++ni)
          acc[mi][ni] = __builtin_amdgcn_mfma_f32_16x16x32_bf16(af[mi], bfr[ni], acc[mi][ni], 0, 0, 0);
    }
    __syncthreads();
  }

#pragma unroll
  for (int mi = 0; mi < 4; ++mi) {
#pragma unroll
    for (int ni = 0; ni < 4; ++ni) {
      const int dbase = m0 + wm * 64 + mi * 16 + lqq * 4;
      const int jj = j0 + wn * 64 + ni * 16 + l16;
      if (MODE == 0) {
#pragma unroll
        for (int r = 0; r < 4; ++r) {
          float v = acc[mi][ni][r] + bias[dbase + r];
          outb[(size_t)(dbase + r) * JTOT + jj] = f2bf(v);
        }
      } else {
        const int t = jj >> 12, n = jj & 4095;
        const int b = n >> 10, hw = n & 1023;
#pragma unroll
        for (int r = 0; r < 4; ++r) {
          size_t o = (((size_t)(b * 512 + dbase + r) * 24 + t) << 10) + hw;
          outf[o] = xres[o] + acc[mi][ni][r] + bias[dbase + r];
        }
      }
    }
  }
}

// ---------------- K3: attention (VALU f32, lane = n, d-pair packed LDS) ----------------
__global__ __launch_bounds__(512) void k_attn(const unsigned short* __restrict__ qkv,
                                              unsigned short* __restrict__ aoC) {
  __shared__ uint32_t kbuf[4][24][64];
  const int ntile = blockIdx.x, h = blockIdx.y;
  const int n0 = ntile * 64;
  const int lane = threadIdx.x & 63, slot = threadIdx.x >> 6;
  const int t0 = slot * 3;
  const size_t baseq = (size_t)(h * 64) * JTOT + n0 + lane;
  const size_t basek = (size_t)(512 + h * 64) * JTOT + n0 + lane;
  const size_t basev = (size_t)(1024 + h * 64) * JTOT + n0 + lane;

  float S[3][24];
#pragma unroll
  for (int a = 0; a < 3; ++a)
#pragma unroll
    for (int s = 0; s < 24; ++s) S[a][s] = 0.f;

  uint32_t kp[12], qp[12];

#pragma unroll
  for (int dp = 0; dp < 4; ++dp)
#pragma unroll
    for (int a = 0; a < 3; ++a) {
      uint32_t klo = qkv[basek + (size_t)(2 * dp) * JTOT + (t0 + a) * NN];
      uint32_t khi = qkv[basek + (size_t)(2 * dp + 1) * JTOT + (t0 + a) * NN];
      kp[dp * 3 + a] = klo | (khi << 16);
      uint32_t qlo = qkv[baseq + (size_t)(2 * dp) * JTOT + (t0 + a) * NN];
      uint32_t qhi = qkv[baseq + (size_t)(2 * dp + 1) * JTOT + (t0 + a) * NN];
      qp[dp * 3 + a] = qlo | (qhi << 16);
    }

  for (int c = 0; c < 8; ++c) {
    const int dc = c * 8;
#pragma unroll
    for (int dp = 0; dp < 4; ++dp)
#pragma unroll
      for (int a = 0; a < 3; ++a)
        kbuf[dp][t0 + a][lane] = kp[dp * 3 + a];
    float qf[3][8];
#pragma unroll
    for (int dp = 0; dp < 4; ++dp)
#pragma unroll
      for (int a = 0; a < 3; ++a) {
        qf[a][2 * dp]     = bflo(qp[dp * 3 + a]);
        qf[a][2 * dp + 1] = bfhi(qp[dp * 3 + a]);
      }
    if (c < 7) {
      const int dn = dc + 8;
#pragma unroll
      for (int dp = 0; dp < 4; ++dp)
#pragma unroll
        for (int a = 0; a < 3; ++a) {
          uint32_t klo = qkv[basek + (size_t)(dn + 2 * dp) * JTOT + (t0 + a) * NN];
          uint32_t khi = qkv[basek + (size_t)(dn + 2 * dp + 1) * JTOT + (t0 + a) * NN];
          kp[dp * 3 + a] = klo | (khi << 16);
          uint32_t qlo = qkv[baseq + (size_t)(dn + 2 * dp) * JTOT + (t0 + a) * NN];
          uint32_t qhi = qkv[baseq + (size_t)(dn + 2 * dp + 1) * JTOT + (t0 + a) * NN];
          qp[dp * 3 + a] = qlo | (qhi << 16);
        }
    }
    __syncthreads();
#pragma unroll
    for (int dp = 0; dp < 4; ++dp) {
#pragma unroll
      for (int s = 0; s < 24; ++s) {
        uint32_t kpr = kbuf[dp][s][lane];
        float k0 = bflo(kpr), k1 = bfhi(kpr);
        S[0][s] = fmaf(qf[0][2 * dp], k0, S[0][s]);
        S[0][s] = fmaf(qf[0][2 * dp + 1], k1, S[0][s]);
        S[1][s] = fmaf(qf[1][2 * dp], k0, S[1][s]);
        S[1][s] = fmaf(qf[1][2 * dp + 1], k1, S[1][s]);
        S[2][s] = fmaf(qf[2][2 * dp], k0, S[2][s]);
        S[2][s] = fmaf(qf[2][2 * dp + 1], k1, S[2][s]);
      }
    }
    __syncthreads();
  }

#pragma unroll
  for (int dp = 0; dp < 4; ++dp)
#pragma unroll
    for (int a = 0; a < 3; ++a) {
      uint32_t vlo = qkv[basev + (size_t)(2 * dp) * JTOT + (t0 + a) * NN];
      uint32_t vhi = qkv[basev + (size_t)(2 * dp + 1) * JTOT + (t0 + a) * NN];
      kp[dp * 3 + a] = vlo | (vhi << 16);
    }

#pragma unroll
  for (int a = 0; a < 3; ++a) {
    float mx = S[a][0];
#pragma unroll
    for (int s = 1; s < 24; ++s) mx = fmaxf(mx, S[a][s]);
    float sum = 0.f;
#pragma unroll
    for (int s = 0; s < 24; ++s) {
      float e = __expf((S[a][s] - mx) * 0.125f);
      S[a][s] = e; sum += e;
    }
    float inv = 1.f / sum;
#pragma unroll
    for (int s = 0; s < 24; ++s) S[a][s] *= inv;
  }

  for (int c = 0; c < 8; ++c) {
    const int dc = c * 8;
#pragma unroll
    for (int dp = 0; dp < 4; ++dp)
#pragma unroll
      for (int a = 0; a < 3; ++a)
        kbuf[dp][t0 + a][lane] = kp[dp * 3 + a];
    if (c < 7) {
      const int dn = dc + 8;
#pragma unroll
      for (int dp = 0; dp < 4; ++dp)
#pragma unroll
        for (int a = 0; a < 3; ++a) {
          uint32_t vlo = qkv[basev + (size_t)(dn + 2 * dp) * JTOT + (t0 + a) * NN];
          uint32_t vhi = qkv[basev + (size_t)(dn + 2 * dp + 1) * JTOT + (t0 + a) * NN];
          kp[dp * 3 + a] = vlo | (vhi << 16);
        }
    }
    __syncthreads();
    float o[3][8];
#pragma unroll
    for (int a = 0; a < 3; ++a)
#pragma unroll
      for (int d = 0; d < 8; ++d) o[a][d] = 0.f;
#pragma unroll
    for (int dp = 0; dp < 4; ++dp) {
#pragma unroll
      for (int s = 0; s < 24; ++s) {
        uint32_t vpr = kbuf[dp][s][lane];
        float v0 = bflo(vpr), v1 = bfhi(vpr);
        o[0][2 * dp]     = fmaf(S[0][s], v0, o[0][2 * dp]);
        o[0][2 * dp + 1] = fmaf(S[0][s], v1, o[0][2 * dp + 1]);
        o[1][2 * dp]     = fmaf(S[1][s], v0, o[1][2 * dp]);
        o[1][2 * dp + 1] = fmaf(S[1][s], v1, o[1][2 * dp + 1]);
        o[2][2 * dp]     = fmaf(S[2][s], v0, o[2][2 * dp]);
        o[2][2 * dp + 1] = fmaf(S[2][s], v1, o[2][2 * dp + 1]);
      }
    }
#pragma unroll
    for (int a = 0; a < 3; ++a) {
      uint4 wv;
      wv.x = pkbf(o[a][0], o[a][1]);
      wv.y = pkbf(o[a][2], o[a][3]);
      wv.z = pkbf(o[a][4], o[a][5]);
      wv.w = pkbf(o[a][6], o[a][7]);
      size_t unit = (size_t)(h * 8 + c) * JTOT + (size_t)(t0 + a) * NN + n0 + lane;
      *reinterpret_cast<uint4*>(&aoC[unit * 8]) = wv;
    }
    __syncthreads();
  }
}

extern "C" void kernel_launch(void* const* d_in, const int* in_sizes, int n_in,
                              void* d_out, int out_size, void* d_ws, size_t ws_size,
                              hipStream_t stream) {
  (void)in_sizes; (void)n_in; (void)out_size; (void)ws_size;
  const float* x     = (const float*)d_in[0];
  const float* gnw   = (const float*)d_in[1];
  const float* gnb   = (const float*)d_in[2];
  const float* qkvw  = (const float*)d_in[3];
  const float* qkvb  = (const float*)d_in[4];
  const float* projw = (const float*)d_in[5];
  const float* projb = (const float*)d_in[6];
  float* out = (float*)d_out;
  char* ws = (char*)d_ws;

  unsigned short* qkvw_bf = (unsigned short*)(ws);                    // 1,572,864 B
  unsigned short* projw_bf = (unsigned short*)(ws + 1572864);         //   524,288 B
  float* mean = (float*)(ws + 2097152);                               //   524,288 B
  float* rstd = (float*)(ws + 2621440);                               //   524,288 B
  unsigned short* xn  = (unsigned short*)(ws + 3145728);              // 100,663,296 B (also attnout chunked)
  unsigned short* qkv = (unsigned short*)(ws + 3145728 + 100663296);  // 301,989,888 B

  k_cvt<<<dim3(3072), dim3(256), 0, stream>>>(qkvw, projw, qkvw_bf, projw_bf);
  k_stats<<<dim3(2048), dim3(256), 0, stream>>>(x, mean, rstd);
  k_norm<<<dim3(1536), dim3(256), 0, stream>>>(x, mean, rstd, gnw, gnb, xn);
  k_gemm8<<<dim3(2304), dim3(512), 0, stream>>>(qkvw_bf, xn, qkvb, qkv);
  k_attn<<<dim3(64, 8), dim3(512), 0, stream>>>(qkv, xn);  // chunked attnout overwrites xn
  k_gemm<1><<<dim3(3072), dim3(256), 0, stream>>>(projw_bf, xn, projb, nullptr, x, out);
}

// Round 6
// 588.591 us; speedup vs baseline: 1.9425x; 1.2942x over previous
//
#include <hip/hip_runtime.h>
#include <hip/hip_bf16.h>
#include <stdint.h>

#define C_    512
#define T_    24
#define HWSZ  1024
#define NN    4096
#define JTOT  98304   // T_*NN
#define EPSV  1e-5f

typedef short short8 __attribute__((ext_vector_type(8)));
typedef short short4v __attribute__((ext_vector_type(4)));
typedef float f32x4 __attribute__((ext_vector_type(4)));

typedef __attribute__((address_space(1))) const uint32_t glob_u32;
typedef __attribute__((address_space(3))) uint32_t lds_u32;

__device__ __forceinline__ unsigned short f2bf(float f) {
  union { float f; unsigned u; } v; v.f = f;
  unsigned r = v.u + 0x7fffu + ((v.u >> 16) & 1u);
  return (unsigned short)(r >> 16);
}
__device__ __forceinline__ float bf2f(unsigned short b) {
  union { unsigned u; float f; } v; v.u = ((unsigned)b) << 16;
  return v.f;
}
__device__ __forceinline__ float bflo(uint32_t u) {
  union { unsigned u; float f; } v; v.u = u << 16; return v.f;
}
__device__ __forceinline__ float bfhi(uint32_t u) {
  union { unsigned u; float f; } v; v.u = u & 0xffff0000u; return v.f;
}
__device__ __forceinline__ uint32_t pkbf(float a, float b) {
  return (uint32_t)f2bf(a) | ((uint32_t)f2bf(b) << 16);
}

__device__ __forceinline__ void gload_lds16(const void* g, void* l) {
  __builtin_amdgcn_global_load_lds((glob_u32*)g, (lds_u32*)l, 16, 0, 0);
}

// ---------------- K0: weight f32 -> bf16 ----------------
__global__ void k_cvt(const float* __restrict__ qkvw, const float* __restrict__ projw,
                      unsigned short* __restrict__ qkvw_bf, unsigned short* __restrict__ projw_bf) {
  int i = blockIdx.x * 256 + threadIdx.x;
  if (i < 786432) qkvw_bf[i] = f2bf(qkvw[i]);
  if (i < 262144) projw_bf[i] = f2bf(projw[i]);
}

// ---------------- K1a: GroupNorm stats ----------------
__global__ __launch_bounds__(256) void k_stats(const float* __restrict__ x,
                                               float* __restrict__ mean, float* __restrict__ rstd) {
  int bid = blockIdx.x;
  int g = bid & 31, hwt = (bid >> 5) & 15, b = bid >> 9;
  int tid = threadIdx.x, lane = tid & 63, grp = tid >> 6;
  int hw = hwt * 64 + lane;
  float s = 0.f, sq = 0.f;
  for (int ct = grp; ct < 384; ct += 4) {
    int c = g * 16 + ct / 24;
    int t = ct % 24;
    float v = x[((size_t)((b * 512 + c) * 24 + t) << 10) + hw];
    s += v; sq += v * v;
  }
  __shared__ float ls[4][64], lq[4][64];
  ls[grp][lane] = s; lq[grp][lane] = sq;
  __syncthreads();
  if (tid < 64) {
    float S = ls[0][tid] + ls[1][tid] + ls[2][tid] + ls[3][tid];
    float Q = lq[0][tid] + lq[1][tid] + lq[2][tid] + lq[3][tid];
    float m = S * (1.f / 384.f);
    float var = Q * (1.f / 384.f) - m * m;
    int n = b * HWSZ + hwt * 64 + tid;
    mean[n * 32 + g] = m;
    rstd[n * 32 + g] = rsqrtf(var + EPSV);
  }
}

// ---------------- K1b: normalize + transpose to Xn[j][c] bf16 (v2) ----------------
// block = (b, t, hwt 16, chalf 2): 64 n x 256 c raw-bf16 LDS tile, 33 KB -> 4 blocks/CU.
// grid 3072, block 256.
__global__ __launch_bounds__(256) void k_norm(const float* __restrict__ x,
                                              const float* __restrict__ mean, const float* __restrict__ rstd,
                                              const float* __restrict__ gnw, const float* __restrict__ gnb,
                                              unsigned short* __restrict__ xn) {
  __shared__ unsigned short xs[64][260];   // row stride 520 B = 130 dwords (2 mod 32)
  const int bid = blockIdx.x;
  const int hwt = bid & 15;
  const int chalf = (bid >> 4) & 1;
  const int tb = bid >> 5;                 // 0..95
  const int t = tb % 24, b = tb / 24;
  const int hw0 = hwt * 64;
  const int tid = threadIdx.x;
  const int w = tid >> 6, lane = tid & 63;

  // ---- phase 1: global float4 -> raw bf16 LDS [n][c]
  const int crel0 = w * 4 + (lane >> 4);   // 0..15
  const int hwr = (lane & 15) * 4;
#pragma unroll
  for (int k = 0; k < 16; ++k) {
    const int crel = k * 16 + crel0;
    const int c = chalf * 256 + crel;
    const float4 v = *reinterpret_cast<const float4*>(
        &x[(((size_t)(b * 512 + c) * 24 + t) << 10) + hw0 + hwr]);
    xs[hwr + 0][crel] = f2bf(v.x);
    xs[hwr + 1][crel] = f2bf(v.y);
    xs[hwr + 2][crel] = f2bf(v.z);
    xs[hwr + 3][crel] = f2bf(v.w);
  }

  // ---- per-lane constants (issued before the barrier to hide latency)
  const int crel8 = (lane & 31) * 8;
  const int c8 = chalf * 256 + crel8;
  const int g = c8 >> 4;
  float gw[8], gb[8];
#pragma unroll
  for (int i = 0; i < 8; ++i) { gw[i] = gnw[c8 + i]; gb[i] = gnb[c8 + i]; }
  float mm[8], rr[8];
#pragma unroll
  for (int p = 0; p < 8; ++p) {
    const int nrel = (p * 4 + w) * 2 + (lane >> 5);
    const int ng = b * HWSZ + hw0 + nrel;
    mm[p] = mean[ng * 32 + g];
    rr[p] = rstd[ng * 32 + g];
  }
  __syncthreads();

  // ---- phase 2: row-contiguous LDS read, normalize, coalesced uint4 store
#pragma unroll
  for (int p = 0; p < 8; ++p) {
    const int nrel = (p * 4 + w) * 2 + (lane >> 5);
    const short4v lo = *reinterpret_cast<const short4v*>(&xs[nrel][crel8]);
    const short4v hi = *reinterpret_cast<const short4v*>(&xs[nrel][crel8 + 4]);
    float y[8];
#pragma unroll
    for (int i = 0; i < 4; ++i) {
      y[i]     = (bf2f((unsigned short)lo[i]) - mm[p]) * rr[p] * gw[i]     + gb[i];
      y[i + 4] = (bf2f((unsigned short)hi[i]) - mm[p]) * rr[p] * gw[i + 4] + gb[i + 4];
    }
    uint4 wv;
    wv.x = pkbf(y[0], y[1]);
    wv.y = pkbf(y[2], y[3]);
    wv.z = pkbf(y[4], y[5]);
    wv.w = pkbf(y[6], y[7]);
    const size_t j = (size_t)t * NN + b * HWSZ + hw0 + nrel;
    *reinterpret_cast<uint4*>(&xn[j * C_ + c8]) = wv;
  }
}

// ---------------- K2: 256x256 8-phase bf16 MFMA GEMM (QKV) ----------------
#define STAGE8(mat, half, tile, Gptr, row0)                                           \
  {                                                                                   \
    unsigned short* _l = &lds[(((tile) & 1) * 2 + (mat))][half][(w * 2) * 512];       \
    const unsigned short* _g = (Gptr) +                                               \
        (size_t)((row0) + (half) * 128 + (w * 2) * 8 + srow) * 512 +                  \
        (tile) * 64 + sslot * 8;                                                      \
    gload_lds16(_g, _l);                                                              \
    gload_lds16(_g + 8 * 512, _l + 512);                                              \
  }

__global__ __launch_bounds__(512, 2) void k_gemm8(
    const unsigned short* __restrict__ A,   // [1536][512] bf16
    const unsigned short* __restrict__ B,   // [JTOT][512] bf16
    const float* __restrict__ bias,         // [1536]
    unsigned short* __restrict__ outb) {    // [1536][JTOT] bf16
  __shared__ __attribute__((aligned(16))) unsigned short lds[4][2][8192];
  const int bid = blockIdx.x;
  const int cpx = 2304 >> 3;
  const int lid = (bid & 7) * cpx + (bid >> 3);
  const int mt = lid % 6, jt = lid / 6;
  const int m0 = mt * 256, j0 = jt * 256;
  const int tid = threadIdx.x;
  const int w = tid >> 6, lane = tid & 63;
  const int l16 = lane & 15, lqq = lane >> 4;
  const int wm = w >> 2, wn = w & 3;
  const int srow = lane >> 3;
  const int sslot = (lane & 7) ^ srow;
  const int k0off = l16 * 64 + ((lqq ^ (l16 & 7)) * 8);
  const int k1off = l16 * 64 + (((lqq + 4) ^ (l16 & 7)) * 8);

  f32x4 acc[8][4];
#pragma unroll
  for (int i = 0; i < 8; ++i)
#pragma unroll
    for (int j = 0; j < 4; ++j) acc[i][j] = {0.f, 0.f, 0.f, 0.f};

  STAGE8(0, 0, 0, A, m0); STAGE8(0, 1, 0, A, m0);
  STAGE8(1, 0, 0, B, j0); STAGE8(1, 1, 0, B, j0);
  STAGE8(0, 0, 1, A, m0); STAGE8(0, 1, 1, A, m0);
  STAGE8(1, 0, 1, B, j0);
  asm volatile("s_waitcnt vmcnt(6)" ::: "memory");
  __builtin_amdgcn_s_barrier();

  for (int t = 0; t < 8; ++t) {
    const int buf = t & 1;
    const unsigned short* Ab = &lds[buf * 2 + 0][wm][0];
    const unsigned short* Bb = &lds[buf * 2 + 1][wn >> 1][(wn & 1) * 4096];
    short8 a[8][2], bb[4][2];
#pragma unroll
    for (int rr = 0; rr < 8; ++rr) {
      a[rr][0] = *reinterpret_cast<const short8*>(Ab + rr * 1024 + k0off);
      a[rr][1] = *reinterpret_cast<const short8*>(Ab + rr * 1024 + k1off);
    }
#pragma unroll
    for (int cc = 0; cc < 2; ++cc) {
      bb[cc][0] = *reinterpret_cast<const short8*>(Bb + cc * 1024 + k0off);
      bb[cc][1] = *reinterpret_cast<const short8*>(Bb + cc * 1024 + k1off);
    }
    if (t < 7) STAGE8(1, 1, t + 1, B, j0);
    asm volatile("" ::: "memory");
    __builtin_amdgcn_s_barrier();
    asm volatile("s_waitcnt lgkmcnt(0)" ::: "memory");
    __builtin_amdgcn_sched_barrier(0);
    __builtin_amdgcn_s_setprio(1);
#pragma unroll
    for (int rr = 0; rr < 4; ++rr)
#pragma unroll
      for (int cc = 0; cc < 2; ++cc) {
        acc[rr][cc] = __builtin_amdgcn_mfma_f32_16x16x32_bf16(a[rr][0], bb[cc][0], acc[rr][cc], 0, 0, 0);
        acc[rr][cc] = __builtin_amdgcn_mfma_f32_16x16x32_bf16(a[rr][1], bb[cc][1], acc[rr][cc], 0, 0, 0);
      }
    __builtin_amdgcn_s_setprio(0);
    asm volatile("" ::: "memory");
    __builtin_amdgcn_s_barrier();
#pragma unroll
    for (int cc = 2; cc < 4; ++cc) {
      bb[cc][0] = *reinterpret_cast<const short8*>(Bb + cc * 1024 + k0off);
      bb[cc][1] = *reinterpret_cast<const short8*>(Bb + cc * 1024 + k1off);
    }
    if (t < 6) STAGE8(0, 0, t + 2, A, m0);
    asm volatile("" ::: "memory");
    __builtin_amdgcn_s_barrier();
    asm volatile("s_waitcnt lgkmcnt(0)" ::: "memory");
    __builtin_amdgcn_sched_barrier(0);
    __builtin_amdgcn_s_setprio(1);
#pragma unroll
    for (int rr = 0; rr < 4; ++rr)
#pragma unroll
      for (int cc = 2; cc < 4; ++cc) {
        acc[rr][cc] = __builtin_amdgcn_mfma_f32_16x16x32_bf16(a[rr][0], bb[cc][0], acc[rr][cc], 0, 0, 0);
        acc[rr][cc] = __builtin_amdgcn_mfma_f32_16x16x32_bf16(a[rr][1], bb[cc][1], acc[rr][cc], 0, 0, 0);
      }
    __builtin_amdgcn_s_setprio(0);
    asm volatile("" ::: "memory");
    __builtin_amdgcn_s_barrier();
    if (t < 6) STAGE8(0, 1, t + 2, A, m0);
    asm volatile("" ::: "memory");
    __builtin_amdgcn_s_barrier();
    __builtin_amdgcn_s_setprio(1);
#pragma unroll
    for (int rr = 4; rr < 8; ++rr)
#pragma unroll
      for (int cc = 0; cc < 2; ++cc) {
        acc[rr][cc] = __builtin_amdgcn_mfma_f32_16x16x32_bf16(a[rr][0], bb[cc][0], acc[rr][cc], 0, 0, 0);
        acc[rr][cc] = __builtin_amdgcn_mfma_f32_16x16x32_bf16(a[rr][1], bb[cc][1], acc[rr][cc], 0, 0, 0);
      }
    __builtin_amdgcn_s_setprio(0);
    asm volatile("" ::: "memory");
    __builtin_amdgcn_s_barrier();
    if (t < 6) STAGE8(1, 0, t + 2, B, j0);
    asm volatile("" ::: "memory");
    __builtin_amdgcn_s_barrier();
    __builtin_amdgcn_s_setprio(1);
#pragma unroll
    for (int rr = 4; rr < 8; ++rr)
#pragma unroll
      for (int cc = 2; cc < 4; ++cc) {
        acc[rr][cc] = __builtin_amdgcn_mfma_f32_16x16x32_bf16(a[rr][0], bb[cc][0], acc[rr][cc], 0, 0, 0);
        acc[rr][cc] = __builtin_amdgcn_mfma_f32_16x16x32_bf16(a[rr][1], bb[cc][1], acc[rr][cc], 0, 0, 0);
      }
    __builtin_amdgcn_s_setprio(0);
    asm volatile("" ::: "memory");
    if (t < 6) {
      asm volatile("s_waitcnt vmcnt(6)" ::: "memory");
    } else if (t == 6) {
      asm volatile("s_waitcnt vmcnt(0)" ::: "memory");
    }
    __builtin_amdgcn_s_barrier();
  }

#pragma unroll
  for (int rr = 0; rr < 8; ++rr) {
#pragma unroll
    for (int cc = 0; cc < 4; ++cc) {
      const int row = m0 + wm * 128 + rr * 16 + lqq * 4;
      const int col = j0 + wn * 64 + cc * 16 + l16;
#pragma unroll
      for (int r = 0; r < 4; ++r) {
        float v = acc[rr][cc][r] + bias[row + r];
        outb[(size_t)(row + r) * JTOT + col] = f2bf(v);
      }
    }
  }
}

// ---------------- K4: bf16 MFMA GEMM (128^2, proj+residual) ----------------
template <int MODE>
__global__ __launch_bounds__(256, 3) void k_gemm(
    const unsigned short* __restrict__ A,
    const unsigned short* __restrict__ B,
    const float* __restrict__ bias,
    unsigned short* __restrict__ outb,
    const float* __restrict__ xres,
    float* __restrict__ outf) {
  __shared__ __attribute__((aligned(16))) unsigned short As[128 * 64];
  __shared__ __attribute__((aligned(16))) unsigned short Bs[128 * 64];
  const int NMT = (MODE == 0) ? 12 : 4;
  const int bid = blockIdx.x;
  const int cpx = gridDim.x >> 3;
  const int lid = (bid & 7) * cpx + (bid >> 3);
  const int mt = lid % NMT, jt = lid / NMT;
  const int j0 = jt * 128, m0 = mt * 128;
  const int tid = threadIdx.x;
  const int wave = tid >> 6, lane = tid & 63;
  const int l16 = lane & 15, lqq = lane >> 4;
  const int wm = wave >> 1, wn = wave & 1;
  const int srow = lane >> 3, sseg = lane & 7;

  f32x4 acc[4][4];
#pragma unroll
  for (int i = 0; i < 4; ++i)
#pragma unroll
    for (int j = 0; j < 4; ++j) acc[i][j] = {0.f, 0.f, 0.f, 0.f};

  for (int kt = 0; kt < 512; kt += 64) {
#pragma unroll
    for (int i = 0; i < 4; ++i) {
      const int chunk = i * 4 + wave;
      const int r = chunk * 8 + srow;
      gload_lds16(A + ((size_t)(m0 + r) * 512 + kt + sseg * 8), &As[chunk * 512]);
    }
    if (MODE == 0) {
#pragma unroll
      for (int i = 0; i < 4; ++i) {
        const int chunk = i * 4 + wave;
        const int r = chunk * 8 + srow;
        gload_lds16(B + ((size_t)(j0 + r) * 512 + kt + sseg * 8), &Bs[chunk * 512]);
      }
    } else {
#pragma unroll
      for (int p = 0; p < 4; ++p) {
        const int u = p * 256 + tid;
        const int kc = u >> 7, jr = u & 127;
        gload_lds16(B + ((size_t)((kt >> 3) + kc) * JTOT + (j0 + jr)) * 8, &Bs[(size_t)u * 8]);
      }
    }
    __syncthreads();
#pragma unroll
    for (int ks = 0; ks < 2; ++ks) {
      short8 af[4], bfr[4];
#pragma unroll
      for (int i = 0; i < 4; ++i)
        af[i] = *reinterpret_cast<const short8*>(&As[(wm * 64 + i * 16 + l16) * 64 + ks * 32 + lqq * 8]);
#pragma unroll
      for (int i = 0; i < 4; ++i) {
        if (MODE == 0)
          bfr[i] = *reinterpret_cast<const short8*>(&Bs[(wn * 64 + i * 16 + l16) * 64 + ks * 32 + lqq * 8]);
        else
          bfr[i] = *reinterpret_cast<const short8*>(&Bs[(((ks * 4 + lqq) * 128) + wn * 64 + i * 16 + l16) * 8]);
      }
#pragma unroll
      for (int mi = 0; mi < 4; ++mi)
#pragma unroll
        for (int ni = 0; ni < 4; ++ni)
          acc[mi][ni] = __builtin_amdgcn_mfma_f32_16x16x32_bf16(af[mi], bfr[ni], acc[mi][ni], 0, 0, 0);
    }
    __syncthreads();
  }

#pragma unroll
  for (int mi = 0; mi < 4; ++mi) {
#pragma unroll
    for (int ni = 0; ni < 4; ++ni) {
      const int dbase = m0 + wm * 64 + mi * 16 + lqq * 4;
      const int jj = j0 + wn * 64 + ni * 16 + l16;
      if (MODE == 0) {
#pragma unroll
        for (int r = 0; r < 4; ++r) {
          float v = acc[mi][ni][r] + bias[dbase + r];
          outb[(size_t)(dbase + r) * JTOT + jj] = f2bf(v);
        }
      } else {
        const int t = jj >> 12, n = jj & 4095;
        const int b = n >> 10, hw = n & 1023;
#pragma unroll
        for (int r = 0; r < 4; ++r) {
          size_t o = (((size_t)(b * 512 + dbase + r) * 24 + t) << 10) + hw;
          outf[o] = xres[o] + acc[mi][ni][r] + bias[dbase + r];
        }
      }
    }
  }
}

// ---------------- K3: attention (VALU f32, lane = n, d-pair packed LDS) ----------------
__global__ __launch_bounds__(512) void k_attn(const unsigned short* __restrict__ qkv,
                                              unsigned short* __restrict__ aoC) {
  __shared__ uint32_t kbuf[4][24][64];
  const int ntile = blockIdx.x, h = blockIdx.y;
  const int n0 = ntile * 64;
  const int lane = threadIdx.x & 63, slot = threadIdx.x >> 6;
  const int t0 = slot * 3;
  const size_t baseq = (size_t)(h * 64) * JTOT + n0 + lane;
  const size_t basek = (size_t)(512 + h * 64) * JTOT + n0 + lane;
  const size_t basev = (size_t)(1024 + h * 64) * JTOT + n0 + lane;

  float S[3][24];
#pragma unroll
  for (int a = 0; a < 3; ++a)
#pragma unroll
    for (int s = 0; s < 24; ++s) S[a][s] = 0.f;

  uint32_t kp[12], qp[12];

#pragma unroll
  for (int dp = 0; dp < 4; ++dp)
#pragma unroll
    for (int a = 0; a < 3; ++a) {
      uint32_t klo = qkv[basek + (size_t)(2 * dp) * JTOT + (t0 + a) * NN];
      uint32_t khi = qkv[basek + (size_t)(2 * dp + 1) * JTOT + (t0 + a) * NN];
      kp[dp * 3 + a] = klo | (khi << 16);
      uint32_t qlo = qkv[baseq + (size_t)(2 * dp) * JTOT + (t0 + a) * NN];
      uint32_t qhi = qkv[baseq + (size_t)(2 * dp + 1) * JTOT + (t0 + a) * NN];
      qp[dp * 3 + a] = qlo | (qhi << 16);
    }

  for (int c = 0; c < 8; ++c) {
    const int dc = c * 8;
#pragma unroll
    for (int dp = 0; dp < 4; ++dp)
#pragma unroll
      for (int a = 0; a < 3; ++a)
        kbuf[dp][t0 + a][lane] = kp[dp * 3 + a];
    float qf[3][8];
#pragma unroll
    for (int dp = 0; dp < 4; ++dp)
#pragma unroll
      for (int a = 0; a < 3; ++a) {
        qf[a][2 * dp]     = bflo(qp[dp * 3 + a]);
        qf[a][2 * dp + 1] = bfhi(qp[dp * 3 + a]);
      }
    if (c < 7) {
      const int dn = dc + 8;
#pragma unroll
      for (int dp = 0; dp < 4; ++dp)
#pragma unroll
        for (int a = 0; a < 3; ++a) {
          uint32_t klo = qkv[basek + (size_t)(dn + 2 * dp) * JTOT + (t0 + a) * NN];
          uint32_t khi = qkv[basek + (size_t)(dn + 2 * dp + 1) * JTOT + (t0 + a) * NN];
          kp[dp * 3 + a] = klo | (khi << 16);
          uint32_t qlo = qkv[baseq + (size_t)(dn + 2 * dp) * JTOT + (t0 + a) * NN];
          uint32_t qhi = qkv[baseq + (size_t)(dn + 2 * dp + 1) * JTOT + (t0 + a) * NN];
          qp[dp * 3 + a] = qlo | (qhi << 16);
        }
    }
    __syncthreads();
#pragma unroll
    for (int dp = 0; dp < 4; ++dp) {
#pragma unroll
      for (int s = 0; s < 24; ++s) {
        uint32_t kpr = kbuf[dp][s][lane];
        float k0 = bflo(kpr), k1 = bfhi(kpr);
        S[0][s] = fmaf(qf[0][2 * dp], k0, S[0][s]);
        S[0][s] = fmaf(qf[0][2 * dp + 1], k1, S[0][s]);
        S[1][s] = fmaf(qf[1][2 * dp], k0, S[1][s]);
        S[1][s] = fmaf(qf[1][2 * dp + 1], k1, S[1][s]);
        S[2][s] = fmaf(qf[2][2 * dp], k0, S[2][s]);
        S[2][s] = fmaf(qf[2][2 * dp + 1], k1, S[2][s]);
      }
    }
    __syncthreads();
  }

#pragma unroll
  for (int dp = 0; dp < 4; ++dp)
#pragma unroll
    for (int a = 0; a < 3; ++a) {
      uint32_t vlo = qkv[basev + (size_t)(2 * dp) * JTOT + (t0 + a) * NN];
      uint32_t vhi = qkv[basev + (size_t)(2 * dp + 1) * JTOT + (t0 + a) * NN];
      kp[dp * 3 + a] = vlo | (vhi << 16);
    }

#pragma unroll
  for (int a = 0; a < 3; ++a) {
    float mx = S[a][0];
#pragma unroll
    for (int s = 1; s < 24; ++s) mx = fmaxf(mx, S[a][s]);
    float sum = 0.f;
#pragma unroll
    for (int s = 0; s < 24; ++s) {
      float e = __expf((S[a][s] - mx) * 0.125f);
      S[a][s] = e; sum += e;
    }
    float inv = 1.f / sum;
#pragma unroll
    for (int s = 0; s < 24; ++s) S[a][s] *= inv;
  }

  for (int c = 0; c < 8; ++c) {
    const int dc = c * 8;
#pragma unroll
    for (int dp = 0; dp < 4; ++dp)
#pragma unroll
      for (int a = 0; a < 3; ++a)
        kbuf[dp][t0 + a][lane] = kp[dp * 3 + a];
    if (c < 7) {
      const int dn = dc + 8;
#pragma unroll
      for (int dp = 0; dp < 4; ++dp)
#pragma unroll
        for (int a = 0; a < 3; ++a) {
          uint32_t vlo = qkv[basev + (size_t)(dn + 2 * dp) * JTOT + (t0 + a) * NN];
          uint32_t vhi = qkv[basev + (size_t)(dn + 2 * dp + 1) * JTOT + (t0 + a) * NN];
          kp[dp * 3 + a] = vlo | (vhi << 16);
        }
    }
    __syncthreads();
    float o[3][8];
#pragma unroll
    for (int a = 0; a < 3; ++a)
#pragma unroll
      for (int d = 0; d < 8; ++d) o[a][d] = 0.f;
#pragma unroll
    for (int dp = 0; dp < 4; ++dp) {
#pragma unroll
      for (int s = 0; s < 24; ++s) {
        uint32_t vpr = kbuf[dp][s][lane];
        float v0 = bflo(vpr), v1 = bfhi(vpr);
        o[0][2 * dp]     = fmaf(S[0][s], v0, o[0][2 * dp]);
        o[0][2 * dp + 1] = fmaf(S[0][s], v1, o[0][2 * dp + 1]);
        o[1][2 * dp]     = fmaf(S[1][s], v0, o[1][2 * dp]);
        o[1][2 * dp + 1] = fmaf(S[1][s], v1, o[1][2 * dp + 1]);
        o[2][2 * dp]     = fmaf(S[2][s], v0, o[2][2 * dp]);
        o[2][2 * dp + 1] = fmaf(S[2][s], v1, o[2][2 * dp + 1]);
      }
    }
#pragma unroll
    for (int a = 0; a < 3; ++a) {
      uint4 wv;
      wv.x = pkbf(o[a][0], o[a][1]);
      wv.y = pkbf(o[a][2], o[a][3]);
      wv.z = pkbf(o[a][4], o[a][5]);
      wv.w = pkbf(o[a][6], o[a][7]);
      size_t unit = (size_t)(h * 8 + c) * JTOT + (size_t)(t0 + a) * NN + n0 + lane;
      *reinterpret_cast<uint4*>(&aoC[unit * 8]) = wv;
    }
    __syncthreads();
  }
}

extern "C" void kernel_launch(void* const* d_in, const int* in_sizes, int n_in,
                              void* d_out, int out_size, void* d_ws, size_t ws_size,
                              hipStream_t stream) {
  (void)in_sizes; (void)n_in; (void)out_size; (void)ws_size;
  const float* x     = (const float*)d_in[0];
  const float* gnw   = (const float*)d_in[1];
  const float* gnb   = (const float*)d_in[2];
  const float* qkvw  = (const float*)d_in[3];
  const float* qkvb  = (const float*)d_in[4];
  const float* projw = (const float*)d_in[5];
  const float* projb = (const float*)d_in[6];
  float* out = (float*)d_out;
  char* ws = (char*)d_ws;

  unsigned short* qkvw_bf = (unsigned short*)(ws);                    // 1,572,864 B
  unsigned short* projw_bf = (unsigned short*)(ws + 1572864);         //   524,288 B
  float* mean = (float*)(ws + 2097152);                               //   524,288 B
  float* rstd = (float*)(ws + 2621440);                               //   524,288 B
  unsigned short* xn  = (unsigned short*)(ws + 3145728);              // 100,663,296 B (also attnout chunked)
  unsigned short* qkv = (unsigned short*)(ws + 3145728 + 100663296);  // 301,989,888 B

  k_cvt<<<dim3(3072), dim3(256), 0, stream>>>(qkvw, projw, qkvw_bf, projw_bf);
  k_stats<<<dim3(2048), dim3(256), 0, stream>>>(x, mean, rstd);
  k_norm<<<dim3(3072), dim3(256), 0, stream>>>(x, mean, rstd, gnw, gnb, xn);
  k_gemm8<<<dim3(2304), dim3(512), 0, stream>>>(qkvw_bf, xn, qkvb, qkv);
  k_attn<<<dim3(64, 8), dim3(512), 0, stream>>>(qkv, xn);  // chunked attnout overwrites xn
  k_gemm<1><<<dim3(3072), dim3(256), 0, stream>>>(projw_bf, xn, projb, nullptr, x, out);
}